// Round 1
// baseline (941.480 us; speedup 1.0000x reference)
//
#include <hip/hip_runtime.h>
#include <cstdint>
#include <cstddef>

#define BB 8
#define SS 4096
#define HH 1024
#define NHH 16
#define HDD 64
#define MM (BB*SS)   // 32768
#define KVSPLIT 16

#define BMt 256
#define BNt 128
#define BKt 64
#define NTt (HH/BKt)  // 16

typedef __attribute__((ext_vector_type(8))) short short8_t;
typedef __attribute__((ext_vector_type(4))) float f32x4;

__device__ __forceinline__ float bf2f(short u) {
  unsigned int x = ((unsigned int)(unsigned short)u) << 16;
  return __uint_as_float(x);
}
__device__ __forceinline__ short f2bf(float f) {
  unsigned int u = __float_as_uint(f);
  u += 0x7FFFu + ((u >> 16) & 1u);
  return (short)(u >> 16);
}

__device__ __forceinline__ void gload_lds16(const void* g, void* l) {
  __builtin_amdgcn_global_load_lds(
      (const __attribute__((address_space(1))) void*)g,
      (__attribute__((address_space(3))) void*)l, 16, 0, 0);
}

// ---------------- fp32 -> bf16 convert (vectorized) ----------------
__global__ void cvt_bf16(const float* __restrict__ in, short* __restrict__ out, int n4) {
  int i = blockIdx.x * blockDim.x + threadIdx.x;
  if (i >= n4) return;
  float4 v = ((const float4*)in)[i];
  short4 o;
  o.x = f2bf(v.x); o.y = f2bf(v.y); o.z = f2bf(v.z); o.w = f2bf(v.w);
  ((short4*)out)[i] = o;
}

// ---------------- 256x128 pipelined GEMM body: C = act(A @ W^T + bias) ----------------
// K = N-stride = HH compile-time. 512 threads / 8 waves (4M x 2N), wave tile 64x64.
// 3-deep circular LDS (144 KiB), counted vmcnt(6) at tile boundaries (T3+T4),
// (row&7) 16B-slot XOR swizzle with inverse-swizzled global source (T2, rule 21),
// s_setprio(1) around MFMA clusters (T5). Coalesced LDS-transposed epilogue.
__device__ __forceinline__ void gemm256_body(
    const short* __restrict__ A, const short* __restrict__ W,
    const float* __restrict__ bias, short* __restrict__ C,
    int m0, int n0, bool act)
{
  __shared__ __align__(16) short sA[3 * BMt * BKt];  // 98304 B
  __shared__ __align__(16) short sB[3 * BNt * BKt];  // 49152 B

  const int tid  = threadIdx.x;
  const int lane = tid & 63;
  const int wm   = (tid >> 6) >> 1;   // 0..3  (M groups of 64 rows)
  const int wn   = (tid >> 6) & 1;    // 0..1  (N groups of 64 cols)
  const int fr   = lane & 15;
  const int fg   = lane >> 4;         // 0..3

  // staging: per 64-row unit, 512 threads x 16B = 8KB; thread -> (row, 16B slot)
  const int urow  = tid >> 3;         // 0..63
  const int uslot = tid & 7;          // 0..7
  // inverse-swizzled global source so swizzled ds_read retrieves logical data
  const short* Asrc = A + (size_t)(m0 + urow) * HH + ((uslot ^ (urow & 7)) << 3);
  const short* Bsrc = W + (size_t)(n0 + urow) * HH + ((uslot ^ (urow & 7)) << 3);
  char* Adst = (char*)sA + tid * 16;  // linear LDS dest (wave-uniform base + lane*16)
  char* Bdst = (char*)sB + tid * 16;

#define STG_A(b, kt, u) gload_lds16(Asrc + (size_t)(u) * 64 * HH + (kt) * 64, Adst + (b) * 32768 + (u) * 8192)
#define STG_B(b, kt, u) gload_lds16(Bsrc + (size_t)(u) * 64 * HH + (kt) * 64, Bdst + (b) * 16384 + (u) * 8192)

  // swizzled fragment-read slot offsets (bytes) for k-slice 0 / 1
  const int swz0 = (( fg)     ^ (fr & 7)) << 4;
  const int swz1 = ((4 + fg)  ^ (fr & 7)) << 4;
  const char* Abase = (const char*)sA + (wm * 64 + fr) * 128;
  const char* Bbase = (const char*)sB + (wn * 64 + fr) * 128;

  f32x4 acc[4][4] = {};

  // prologue: stage tiles 0 and 1 (12 loads), wait tile 0 (6 stay in flight)
  STG_A(0, 0, 0); STG_A(0, 0, 1); STG_A(0, 0, 2); STG_A(0, 0, 3);
  STG_B(0, 0, 0); STG_B(0, 0, 1);
  STG_A(1, 1, 0); STG_A(1, 1, 1); STG_A(1, 1, 2); STG_A(1, 1, 3);
  STG_B(1, 1, 0); STG_B(1, 1, 1);
  asm volatile("s_waitcnt vmcnt(6)" ::: "memory");
  __builtin_amdgcn_s_barrier();

  int buf = 0;
  for (int t = 0; t < NTt; ++t) {
    const int nb   = (buf >= 1) ? buf - 1 : 2;   // (buf+2)%3 — holds tile t-1 (dead)
    const int aoff = buf * 32768;
    const int boff = buf * 16384;
    const bool pf  = (t + 2 < NTt);

    // ---- phase 0 (k-slice 0) ----
    if (pf) { STG_A(nb, t + 2, 0); STG_A(nb, t + 2, 1); STG_B(nb, t + 2, 0); }
    {
      short8_t af[4], bfr[4];
      #pragma unroll
      for (int i = 0; i < 4; i++) af[i]  = *(const short8_t*)(Abase + aoff + i * 2048 + swz0);
      #pragma unroll
      for (int j = 0; j < 4; j++) bfr[j] = *(const short8_t*)(Bbase + boff + j * 2048 + swz0);
      __builtin_amdgcn_s_barrier();
      __builtin_amdgcn_s_setprio(1);
      #pragma unroll
      for (int i = 0; i < 4; i++) {
        #pragma unroll
        for (int j = 0; j < 4; j++)
          acc[i][j] = __builtin_amdgcn_mfma_f32_16x16x32_bf16(af[i], bfr[j], acc[i][j], 0, 0, 0);
      }
      __builtin_amdgcn_s_setprio(0);
      __builtin_amdgcn_s_barrier();
    }

    // ---- phase 1 (k-slice 1) ----
    if (pf) { STG_A(nb, t + 2, 2); STG_A(nb, t + 2, 3); STG_B(nb, t + 2, 1); }
    {
      short8_t af[4], bfr[4];
      #pragma unroll
      for (int i = 0; i < 4; i++) af[i]  = *(const short8_t*)(Abase + aoff + i * 2048 + swz1);
      #pragma unroll
      for (int j = 0; j < 4; j++) bfr[j] = *(const short8_t*)(Bbase + boff + j * 2048 + swz1);
      __builtin_amdgcn_s_barrier();
      __builtin_amdgcn_s_setprio(1);
      #pragma unroll
      for (int i = 0; i < 4; i++) {
        #pragma unroll
        for (int j = 0; j < 4; j++)
          acc[i][j] = __builtin_amdgcn_mfma_f32_16x16x32_bf16(af[i], bfr[j], acc[i][j], 0, 0, 0);
      }
      __builtin_amdgcn_s_setprio(0);
      // counted drain: tile t+1 resident, tile t+2's 6 loads stay in flight
      if (pf) asm volatile("s_waitcnt vmcnt(6)" ::: "memory");
      else    asm volatile("s_waitcnt vmcnt(0)" ::: "memory");
      __builtin_amdgcn_s_barrier();
    }
    buf = (buf == 2) ? 0 : buf + 1;
  }
#undef STG_A
#undef STG_B

  // ---- epilogue: bias + act, transpose via LDS (reuse sA), coalesced short8 stores ----
  short* sC = sA;  // needs 256*136*2 = 69632 B <= 98304 B
  const int cr = fg * 4;
  float bvj[4];
  #pragma unroll
  for (int j = 0; j < 4; j++) bvj[j] = bias[n0 + wn * 64 + j * 16 + fr];
  #pragma unroll
  for (int j = 0; j < 4; j++) {
    const int col = wn * 64 + j * 16 + fr;
    #pragma unroll
    for (int i = 0; i < 4; i++) {
      const int row = wm * 64 + i * 16 + cr;
      #pragma unroll
      for (int r = 0; r < 4; r++) {
        float v = acc[i][j][r] + bvj[j];
        if (act) v = (v > 0.f) ? (v + 1.f) : __expf(v);
        sC[(row + r) * 136 + col] = f2bf(v);
      }
    }
  }
  __builtin_amdgcn_s_barrier();
  const int orow = tid >> 4;          // 0..31
  const int oc8  = (tid & 15) << 3;   // 0..120 step 8
  #pragma unroll
  for (int p = 0; p < 8; p++) {
    const int row = p * 32 + orow;
    *(short8_t*)(C + (size_t)(m0 + row) * HH + n0 + oc8) =
        *(const short8_t*)(sC + row * 136 + oc8);
  }
}

// fused QKV: blockIdx.x = which*8 + ncol; consecutive x-blocks share the A tile (L2 reuse)
__global__ __launch_bounds__(512, 2) void qkv_gemm(
    const short* __restrict__ xb,
    const short* __restrict__ Wqb, const short* __restrict__ Wkb, const short* __restrict__ Wvb,
    const float* __restrict__ bq, const float* __restrict__ bk, const float* __restrict__ bv,
    short* __restrict__ Qo, short* __restrict__ Ko, short* __restrict__ Vo)
{
  const int which = blockIdx.x >> 3;
  const int n0 = (blockIdx.x & 7) * BNt;
  const int m0 = blockIdx.y * BMt;
  const short* W  = (which == 0) ? Wqb : (which == 1) ? Wkb : Wvb;
  const float* bs = (which == 0) ? bq  : (which == 1) ? bk  : bv;
  short* C        = (which == 0) ? Qo  : (which == 1) ? Ko  : Vo;
  gemm256_body(xb, W, bs, C, m0, n0, which < 2);
}

__global__ __launch_bounds__(512, 2) void dproj_gemm(
    const short* __restrict__ A, const short* __restrict__ W,
    const float* __restrict__ bias, short* __restrict__ C)
{
  gemm256_body(A, W, bias, C, blockIdx.y * BMt, blockIdx.x * BNt, false);
}

// ---------------- kv partials over S-splits ----------------
__global__ __launch_bounds__(256) void kv_part_kernel(
    const short* __restrict__ K_, const short* __restrict__ V_,
    float* __restrict__ kvpart, float* __restrict__ kspart)
{
  __shared__ __align__(16) float sK[32 * 64];
  __shared__ __align__(16) float sV[32 * 64];
  const int h = blockIdx.x, b = blockIdx.y, sp = blockIdx.z;
  const int t = threadIdx.x;
  const int m = t & 63;
  const int dg = (t >> 6) * 16;
  const int lrow = t >> 3;
  const int lcol = (t & 7) * 8;
  const int SC = SS / KVSPLIT;
  float acc[16] = {};
  float ks = 0.f;
  const size_t base = ((size_t)b * SS + (size_t)sp * SC) * HH + (size_t)h * HDD;
  const short* Kp = K_ + base + (size_t)lrow * HH + lcol;
  const short* Vp = V_ + base + (size_t)lrow * HH + lcol;

  for (int sc = 0; sc < SC; sc += 32) {
    short8_t k8 = *(const short8_t*)(Kp + (size_t)sc * HH);
    short8_t v8 = *(const short8_t*)(Vp + (size_t)sc * HH);
    __syncthreads();
    #pragma unroll
    for (int j = 0; j < 8; j++) {
      sK[lrow * 64 + lcol + j] = bf2f(k8[j]);
      sV[lrow * 64 + lcol + j] = bf2f(v8[j]);
    }
    __syncthreads();
    if (t < 64) {
      #pragma unroll
      for (int ss = 0; ss < 32; ss++) ks += sK[ss * 64 + t];
    }
    #pragma unroll 4
    for (int ss = 0; ss < 32; ss++) {
      const float vm = sV[ss * 64 + m];
      const float* kr = sK + ss * 64 + dg;
      #pragma unroll
      for (int j = 0; j < 16; j++) acc[j] += kr[j] * vm;
    }
  }

  const int bh = b * NHH + h;
  float* kvp = kvpart + (size_t)(bh * KVSPLIT + sp) * 4096 + m * 64 + dg;
  #pragma unroll
  for (int j = 0; j < 16; j += 4) {
    f32x4 o;
    o[0] = acc[j]; o[1] = acc[j+1]; o[2] = acc[j+2]; o[3] = acc[j+3];
    *(f32x4*)(kvp + j) = o;
  }
  if (t < 64) kspart[(bh * KVSPLIT + sp) * 64 + t] = ks;
}

// ---------------- reduce partials -> kv bf16 [bh][m][d], ksum fp32 ----------------
__global__ __launch_bounds__(256) void kv_reduce_kernel(
    const float* __restrict__ kvpart, const float* __restrict__ kspart,
    short* __restrict__ kvbf, float* __restrict__ ksum)
{
  const int bh = blockIdx.x;
  const int t = threadIdx.x;
  const float* src = kvpart + (size_t)bh * KVSPLIT * 4096;
  #pragma unroll
  for (int i = 0; i < 4; i++) {
    const int idx = t + i * 256;  // f32x4 index within 4096
    f32x4 s = {};
    #pragma unroll 4
    for (int p = 0; p < KVSPLIT; p++)
      s += ((const f32x4*)(src + (size_t)p * 4096))[idx];
    short4 o;
    o.x = f2bf(s[0]); o.y = f2bf(s[1]); o.z = f2bf(s[2]); o.w = f2bf(s[3]);
    ((short4*)(kvbf + (size_t)bh * 4096))[idx] = o;
  }
  if (t < 64) {
    float s = 0.f;
    #pragma unroll
    for (int p = 0; p < KVSPLIT; p++) s += kspart[(bh * KVSPLIT + p) * 64 + t];
    ksum[bh * 64 + t] = s + 1e-6f;
  }
}

// ---------------- ctx via MFMA: per (b,h), ctx = diag(z) . Q[4096x64] @ kv[64x64]^T ----------------
__global__ __launch_bounds__(256) void ctx_mfma(
    const short* __restrict__ Q, const short* __restrict__ kvbf,
    const float* __restrict__ ksum, short* __restrict__ ctx)
{
  __shared__ __align__(16) short sB[64 * 72];
  __shared__ float sks[64];
  __shared__ float sz[256];
  const int b = blockIdx.z, h = blockIdx.y;
  const int t = threadIdx.x;
  const int lane = t & 63, wave = t >> 6;
  const int s0 = blockIdx.x * 256;
  const int bh = b * NHH + h;

  { // stage kv -> LDS (padded)
    const short8_t* src = (const short8_t*)(kvbf + (size_t)bh * 4096);
    const int m = t >> 2, c = (t & 3) * 16;
    short8_t v0 = src[t * 2], v1 = src[t * 2 + 1];
    *(short8_t*)(sB + m * 72 + c)     = v0;
    *(short8_t*)(sB + m * 72 + c + 8) = v1;
  }
  if (t < 64) sks[t] = ksum[bh * 64 + t];
  __syncthreads();

  { // per-token normalizer z = 1/(q . ksum)
    const short* qp = Q + (size_t)(b * SS + s0 + t) * HH + h * HDD;
    float zden = 0.f;
    #pragma unroll
    for (int i = 0; i < 8; i++) {
      short8_t q8 = *(const short8_t*)(qp + i * 8);
      #pragma unroll
      for (int j = 0; j < 8; j++) zden += bf2f(q8[j]) * sks[i * 8 + j];
    }
    sz[t] = 1.f / zden;
  }
  __syncthreads();

  const int fr = lane & 15, fk = (lane >> 4) * 8;
  const int wrow = wave * 64;
  f32x4 acc[4][4] = {};
  const short* qbase = Q + (size_t)(b * SS + s0 + wrow + fr) * HH + h * HDD + fk;
  #pragma unroll
  for (int k0 = 0; k0 < 64; k0 += 32) {
    short8_t af[4], wf[4];
    #pragma unroll
    for (int i = 0; i < 4; i++)
      af[i] = *(const short8_t*)(qbase + (size_t)(i * 16) * HH + k0);
    #pragma unroll
    for (int j = 0; j < 4; j++)
      wf[j] = *(const short8_t*)(sB + (j * 16 + fr) * 72 + fk + k0);
    #pragma unroll
    for (int i = 0; i < 4; i++) {
      #pragma unroll
      for (int j = 0; j < 4; j++) {
        acc[i][j] = __builtin_amdgcn_mfma_f32_16x16x32_bf16(af[i], wf[j], acc[i][j], 0, 0, 0);
      }
    }
  }

  const int cr = (lane >> 4) * 4, cc = lane & 15;
  short* cp = ctx + ((size_t)(b * SS + s0)) * HH + h * HDD;
  #pragma unroll
  for (int j = 0; j < 4; j++) {
    const int col = j * 16 + cc;
    #pragma unroll
    for (int i = 0; i < 4; i++) {
      #pragma unroll
      for (int r = 0; r < 4; r++) {
        const int row = wrow + i * 16 + cr + r;
        cp[(size_t)row * HH + col] = f2bf(acc[i][j][r] * sz[row]);
      }
    }
  }
}

// ---------------- LayerNorm(P + x) * gamma + beta ----------------
__global__ __launch_bounds__(256) void ln_kernel(
    const short* __restrict__ P, const float* __restrict__ x,
    const float* __restrict__ gamma, const float* __restrict__ beta,
    float* __restrict__ out)
{
  const int row = blockIdx.x;
  const int t = threadIdx.x;
  const short* pr = P + (size_t)row * HH;
  const float* xr = x + (size_t)row * HH;
  short4 p4 = ((const short4*)pr)[t];
  float4 x4 = ((const float4*)xr)[t];
  float h0 = bf2f(p4.x) + x4.x;
  float h1 = bf2f(p4.y) + x4.y;
  float h2 = bf2f(p4.z) + x4.z;
  float h3 = bf2f(p4.w) + x4.w;
  float s1 = h0 + h1 + h2 + h3;
  float s2 = h0*h0 + h1*h1 + h2*h2 + h3*h3;
  #pragma unroll
  for (int o = 32; o > 0; o >>= 1) {
    s1 += __shfl_xor(s1, o);
    s2 += __shfl_xor(s2, o);
  }
  __shared__ float red[8];
  const int wv = t >> 6, ln = t & 63;
  if (ln == 0) { red[wv] = s1; red[4 + wv] = s2; }
  __syncthreads();
  const float S1 = red[0] + red[1] + red[2] + red[3];
  const float S2 = red[4] + red[5] + red[6] + red[7];
  const float mu  = S1 * (1.f / HH);
  const float var = S2 * (1.f / HH) - mu * mu;
  const float inv = rsqrtf(var + 1e-12f);
  float4 g4 = ((const float4*)gamma)[t];
  float4 b4 = ((const float4*)beta)[t];
  float4 o4;
  o4.x = (h0 - mu) * inv * g4.x + b4.x;
  o4.y = (h1 - mu) * inv * g4.y + b4.y;
  o4.z = (h2 - mu) * inv * g4.z + b4.z;
  o4.w = (h3 - mu) * inv * g4.w + b4.w;
  ((float4*)(out + (size_t)row * HH))[t] = o4;
}

extern "C" void kernel_launch(void* const* d_in, const int* in_sizes, int n_in,
                              void* d_out, int out_size, void* d_ws, size_t ws_size,
                              hipStream_t stream)
{
  const float* x     = (const float*)d_in[0];
  // d_in[1] = attention_mask: unused (all zeros; reference ignores it)
  const float* Wq    = (const float*)d_in[2];
  const float* bq    = (const float*)d_in[3];
  const float* Wk    = (const float*)d_in[4];
  const float* bk    = (const float*)d_in[5];
  const float* Wv    = (const float*)d_in[6];
  const float* bv    = (const float*)d_in[7];
  const float* Wd    = (const float*)d_in[8];
  const float* bd    = (const float*)d_in[9];
  const float* gamma = (const float*)d_in[10];
  const float* beta  = (const float*)d_in[11];
  float* out = (float*)d_out;

  char* ws = (char*)d_ws;
  const size_t MB64 = 67108864;
  short* xb  = (short*)(ws + 0 * MB64);
  short* Qb  = (short*)(ws + 1 * MB64);
  short* Kb  = (short*)(ws + 2 * MB64);
  short* Vb  = (short*)(ws + 3 * MB64);
  short* Cb  = (short*)(ws + 4 * MB64);
  short* Wqb = (short*)(ws + 5 * MB64 + 0 * 2097152);
  short* Wkb = (short*)(ws + 5 * MB64 + 1 * 2097152);
  short* Wvb = (short*)(ws + 5 * MB64 + 2 * 2097152);
  short* Wdb = (short*)(ws + 5 * MB64 + 3 * 2097152);
  short* kvbf= (short*)(ws + 5 * MB64 + 4 * 2097152);
  float* ksb = (float*)(ws + 5 * MB64 + 5 * 2097152);
  // kv partials overlay Cb region (not live until ctx_mfma)
  float* kvpart = (float*)(ws + 4 * MB64);
  float* kspart = kvpart + (size_t)128 * KVSPLIT * 4096;
  short* Pb  = Qb;  // Q dead after ctx_mfma

  cvt_bf16<<<(MM * HH / 4) / 256, 256, 0, stream>>>(x,  xb,  MM * HH / 4);
  cvt_bf16<<<(HH * HH / 4) / 256, 256, 0, stream>>>(Wq, Wqb, HH * HH / 4);
  cvt_bf16<<<(HH * HH / 4) / 256, 256, 0, stream>>>(Wk, Wkb, HH * HH / 4);
  cvt_bf16<<<(HH * HH / 4) / 256, 256, 0, stream>>>(Wv, Wvb, HH * HH / 4);
  cvt_bf16<<<(HH * HH / 4) / 256, 256, 0, stream>>>(Wd, Wdb, HH * HH / 4);

  qkv_gemm<<<dim3(24, MM / BMt), 512, 0, stream>>>(xb, Wqb, Wkb, Wvb, bq, bk, bv, Qb, Kb, Vb);

  kv_part_kernel<<<dim3(NHH, BB, KVSPLIT), 256, 0, stream>>>(Kb, Vb, kvpart, kspart);
  kv_reduce_kernel<<<BB * NHH, 256, 0, stream>>>(kvpart, kspart, kvbf, ksb);
  ctx_mfma<<<dim3(SS / 256, NHH, BB), 256, 0, stream>>>(Qb, kvbf, ksb, Cb);

  dproj_gemm<<<dim3(HH / BNt, MM / BMt), 512, 0, stream>>>(Cb, Wdb, bd, Pb);
  ln_kernel<<<MM, 256, 0, stream>>>(Pb, x, gamma, beta, out);
}

// Round 3
// 753.668 us; speedup vs baseline: 1.2492x; 1.2492x over previous
//
#include <hip/hip_runtime.h>
#include <cstdint>
#include <cstddef>

#define BB 8
#define SS 4096
#define HH 1024
#define NHH 16
#define HDD 64
#define MM (BB*SS)   // 32768
#define KVSPLIT 16

#define BMt 256
#define BNt 256
#define BKt 64
#define NTt (HH/BKt)  // 16

typedef __attribute__((ext_vector_type(8))) short short8_t;
typedef __attribute__((ext_vector_type(4))) float f32x4;

__device__ __forceinline__ float bf2f(short u) {
  unsigned int x = ((unsigned int)(unsigned short)u) << 16;
  return __uint_as_float(x);
}
__device__ __forceinline__ short f2bf(float f) {
  unsigned int u = __float_as_uint(f);
  u += 0x7FFFu + ((u >> 16) & 1u);
  return (short)(u >> 16);
}

__device__ __forceinline__ void gload_lds16(const void* g, void* l) {
  __builtin_amdgcn_global_load_lds(
      (const __attribute__((address_space(1))) void*)g,
      (__attribute__((address_space(3))) void*)l, 16, 0, 0);
}

// ---------------- fp32 -> bf16 convert (vectorized) ----------------
__global__ void cvt_bf16(const float* __restrict__ in, short* __restrict__ out, int n4) {
  int i = blockIdx.x * blockDim.x + threadIdx.x;
  if (i >= n4) return;
  float4 v = ((const float4*)in)[i];
  short4 o;
  o.x = f2bf(v.x); o.y = f2bf(v.y); o.z = f2bf(v.z); o.w = f2bf(v.w);
  ((short4*)out)[i] = o;
}

// ---------------- 256x256 4-phase GEMM body: C = act(A @ W^T + bias) ----------------
// m201-geometry. 512 threads / 8 waves (2M x 4N), wave tile 128x64 (acc 8x4).
// 2-buffer LDS (128 KiB). Per K-tile 4 phases {ds_read -> [q0: stage t+1] ->
// barrier -> sched_barrier(0) fence -> setprio(1) -> 16 MFMA -> setprio(0) ->
// barrier -> sched_barrier(0)}; single vmcnt(0) at q3 (loads ~3.5 phases old).
// B-frags register-resident across row-halves. (slot ^ row&7) LDS swizzle with
// inverse-swizzled global source (both-sides rule).
__device__ __forceinline__ void gemm256_body(
    const short* __restrict__ A, const short* __restrict__ W,
    const float* __restrict__ bias, short* __restrict__ C,
    int m0, int n0, bool act)
{
  __shared__ __align__(16) char smem[131072];  // [A: 2x32KB][B: 2x32KB]

  const int tid  = threadIdx.x;
  const int lane = tid & 63;
  const int wm   = (tid >> 6) >> 2;   // 0..1  (128-row half)
  const int wn   = (tid >> 6) & 3;    // 0..3  (64-col group)
  const int fr   = lane & 15;
  const int fg   = lane >> 4;         // 0..3

  // staging: unit = 64 rows x 64 shorts (8KB); thread -> (row=tid>>3, slot=tid&7)
  const int urow  = tid >> 3;
  const int uslot = tid & 7;
  const short* Asrc = A + (size_t)(m0 + urow) * HH + ((uslot ^ (urow & 7)) << 3);
  const short* Bsrc = W + (size_t)(n0 + urow) * HH + ((uslot ^ (urow & 7)) << 3);
  char* Adst = smem + tid * 16;            // linear LDS dest
  char* Bdst = smem + 65536 + tid * 16;

#define STG8(b, kt) do { \
    gload_lds16(Asrc + (size_t)(0*64) * HH + (kt) * 64, Adst + (b) * 32768 + 0*8192); \
    gload_lds16(Asrc + (size_t)(1*64) * HH + (kt) * 64, Adst + (b) * 32768 + 1*8192); \
    gload_lds16(Asrc + (size_t)(2*64) * HH + (kt) * 64, Adst + (b) * 32768 + 2*8192); \
    gload_lds16(Asrc + (size_t)(3*64) * HH + (kt) * 64, Adst + (b) * 32768 + 3*8192); \
    gload_lds16(Bsrc + (size_t)(0*64) * HH + (kt) * 64, Bdst + (b) * 32768 + 0*8192); \
    gload_lds16(Bsrc + (size_t)(1*64) * HH + (kt) * 64, Bdst + (b) * 32768 + 1*8192); \
    gload_lds16(Bsrc + (size_t)(2*64) * HH + (kt) * 64, Bdst + (b) * 32768 + 2*8192); \
    gload_lds16(Bsrc + (size_t)(3*64) * HH + (kt) * 64, Bdst + (b) * 32768 + 3*8192); \
  } while (0)

  // ds_read bases: LDS byte = buf*32768 + row*128 + (slot ^ (row&7))*16
  const char* pA = smem + (wm * 128 + fr) * 128;
  const char* pB = smem + 65536 + (wn * 64 + fr) * 128;
  const int sw0 = ((fg)     ^ (fr & 7)) << 4;   // k-slice 0 slots 0..3
  const int sw1 = ((4 + fg) ^ (fr & 7)) << 4;   // k-slice 1 slots 4..7

  f32x4 acc[8][4] = {};
  short8_t bfrag[2][4];

  // prologue: stage tile 0 into buf 0
  STG8(0, 0);
  asm volatile("s_waitcnt vmcnt(0)" ::: "memory");
  __builtin_amdgcn_s_barrier();
  __builtin_amdgcn_sched_barrier(0);

  #pragma unroll 2
  for (int kt = 0; kt < NTt; ++kt) {
    const int buf = kt & 1;
    const int ao = buf * 32768;
    short8_t af[4];

    // ---- q0: RH0, ks0 (+ stage next tile) ----
    #pragma unroll
    for (int j = 0; j < 4; j++) bfrag[0][j] = *(const short8_t*)(pB + ao + j * 2048 + sw0);
    #pragma unroll
    for (int i = 0; i < 4; i++) af[i] = *(const short8_t*)(pA + ao + i * 2048 + sw0);
    if (kt + 1 < NTt) STG8(buf ^ 1, kt + 1);
    __builtin_amdgcn_s_barrier();
    __builtin_amdgcn_sched_barrier(0);
    __builtin_amdgcn_s_setprio(1);
    #pragma unroll
    for (int i = 0; i < 4; i++)
      #pragma unroll
      for (int j = 0; j < 4; j++)
        acc[i][j] = __builtin_amdgcn_mfma_f32_16x16x32_bf16(af[i], bfrag[0][j], acc[i][j], 0, 0, 0);
    __builtin_amdgcn_s_setprio(0);
    __builtin_amdgcn_s_barrier();
    __builtin_amdgcn_sched_barrier(0);

    // ---- q1: RH0, ks1 ----
    #pragma unroll
    for (int j = 0; j < 4; j++) bfrag[1][j] = *(const short8_t*)(pB + ao + j * 2048 + sw1);
    #pragma unroll
    for (int i = 0; i < 4; i++) af[i] = *(const short8_t*)(pA + ao + i * 2048 + sw1);
    __builtin_amdgcn_s_barrier();
    __builtin_amdgcn_sched_barrier(0);
    __builtin_amdgcn_s_setprio(1);
    #pragma unroll
    for (int i = 0; i < 4; i++)
      #pragma unroll
      for (int j = 0; j < 4; j++)
        acc[i][j] = __builtin_amdgcn_mfma_f32_16x16x32_bf16(af[i], bfrag[1][j], acc[i][j], 0, 0, 0);
    __builtin_amdgcn_s_setprio(0);
    __builtin_amdgcn_s_barrier();
    __builtin_amdgcn_sched_barrier(0);

    // ---- q2: RH1, ks0 (B reused from regs) ----
    #pragma unroll
    for (int i = 0; i < 4; i++) af[i] = *(const short8_t*)(pA + ao + 8192 + i * 2048 + sw0);
    __builtin_amdgcn_s_barrier();
    __builtin_amdgcn_sched_barrier(0);
    __builtin_amdgcn_s_setprio(1);
    #pragma unroll
    for (int i = 0; i < 4; i++)
      #pragma unroll
      for (int j = 0; j < 4; j++)
        acc[4 + i][j] = __builtin_amdgcn_mfma_f32_16x16x32_bf16(af[i], bfrag[0][j], acc[4 + i][j], 0, 0, 0);
    __builtin_amdgcn_s_setprio(0);
    __builtin_amdgcn_s_barrier();
    __builtin_amdgcn_sched_barrier(0);

    // ---- q3: RH1, ks1 (+ drain: staged loads are ~3.5 phases old) ----
    #pragma unroll
    for (int i = 0; i < 4; i++) af[i] = *(const short8_t*)(pA + ao + 8192 + i * 2048 + sw1);
    __builtin_amdgcn_s_barrier();
    __builtin_amdgcn_sched_barrier(0);
    __builtin_amdgcn_s_setprio(1);
    #pragma unroll
    for (int i = 0; i < 4; i++)
      #pragma unroll
      for (int j = 0; j < 4; j++)
        acc[4 + i][j] = __builtin_amdgcn_mfma_f32_16x16x32_bf16(af[i], bfrag[1][j], acc[4 + i][j], 0, 0, 0);
    __builtin_amdgcn_s_setprio(0);
    asm volatile("s_waitcnt vmcnt(0)" ::: "memory");
    __builtin_amdgcn_s_barrier();
    __builtin_amdgcn_sched_barrier(0);
  }
#undef STG8

  // ---- epilogue: bias+act, two-pass LDS transpose (stride 264), short8 stores ----
  short* sC = (short*)smem;   // 128 x 264 x 2B = 67584 B
  float bvj[4];
  #pragma unroll
  for (int j = 0; j < 4; j++) bvj[j] = bias[n0 + wn * 64 + j * 16 + fr];

  #pragma unroll
  for (int h = 0; h < 2; ++h) {
    if (wm == h) {
      #pragma unroll
      for (int ii = 0; ii < 8; ii++) {
        const int rel = (ii >> 2) * 64 + (ii & 3) * 16 + fg * 4;
        #pragma unroll
        for (int j = 0; j < 4; j++) {
          const int col = wn * 64 + j * 16 + fr;
          #pragma unroll
          for (int r = 0; r < 4; r++) {
            float v = acc[ii][j][r] + bvj[j];
            if (act) v = (v > 0.f) ? (v + 1.f) : __expf(v);
            sC[(rel + r) * 264 + col] = f2bf(v);
          }
        }
      }
    }
    __syncthreads();
    const int crow = tid >> 5;          // 0..15
    const int cch  = (tid & 31) * 8;    // short offset, 32 x 16B = 512B row
    #pragma unroll
    for (int p = 0; p < 8; p++) {
      const int row = p * 16 + crow;
      *(short8_t*)(C + (size_t)(m0 + h * 128 + row) * HH + n0 + cch) =
          *(const short8_t*)(sC + row * 264 + cch);
    }
    __syncthreads();
  }
}

// fused QKV: blockIdx.x = which*4 + ncol; consecutive x-blocks share the A tile (L2 reuse)
__global__ __launch_bounds__(512, 2) void qkv_gemm(
    const short* __restrict__ xb,
    const short* __restrict__ Wqb, const short* __restrict__ Wkb, const short* __restrict__ Wvb,
    const float* __restrict__ bq, const float* __restrict__ bk, const float* __restrict__ bv,
    short* __restrict__ Qo, short* __restrict__ Ko, short* __restrict__ Vo)
{
  const int which = blockIdx.x >> 2;
  const int n0 = (blockIdx.x & 3) * BNt;
  const int m0 = blockIdx.y * BMt;
  const short* W  = (which == 0) ? Wqb : (which == 1) ? Wkb : Wvb;
  const float* bs = (which == 0) ? bq  : (which == 1) ? bk  : bv;
  short* C        = (which == 0) ? Qo  : (which == 1) ? Ko  : Vo;
  gemm256_body(xb, W, bs, C, m0, n0, which < 2);
}

__global__ __launch_bounds__(512, 2) void dproj_gemm(
    const short* __restrict__ A, const short* __restrict__ W,
    const float* __restrict__ bias, short* __restrict__ C)
{
  gemm256_body(A, W, bias, C, blockIdx.y * BMt, blockIdx.x * BNt, false);
}

// ---------------- kv partials over S-splits ----------------
__global__ __launch_bounds__(256) void kv_part_kernel(
    const short* __restrict__ K_, const short* __restrict__ V_,
    float* __restrict__ kvpart, float* __restrict__ kspart)
{
  __shared__ __align__(16) float sK[32 * 64];
  __shared__ __align__(16) float sV[32 * 64];
  const int h = blockIdx.x, b = blockIdx.y, sp = blockIdx.z;
  const int t = threadIdx.x;
  const int m = t & 63;
  const int dg = (t >> 6) * 16;
  const int lrow = t >> 3;
  const int lcol = (t & 7) * 8;
  const int SC = SS / KVSPLIT;
  float acc[16] = {};
  float ks = 0.f;
  const size_t base = ((size_t)b * SS + (size_t)sp * SC) * HH + (size_t)h * HDD;
  const short* Kp = K_ + base + (size_t)lrow * HH + lcol;
  const short* Vp = V_ + base + (size_t)lrow * HH + lcol;

  for (int sc = 0; sc < SC; sc += 32) {
    short8_t k8 = *(const short8_t*)(Kp + (size_t)sc * HH);
    short8_t v8 = *(const short8_t*)(Vp + (size_t)sc * HH);
    __syncthreads();
    #pragma unroll
    for (int j = 0; j < 8; j++) {
      sK[lrow * 64 + lcol + j] = bf2f(k8[j]);
      sV[lrow * 64 + lcol + j] = bf2f(v8[j]);
    }
    __syncthreads();
    if (t < 64) {
      #pragma unroll
      for (int ss = 0; ss < 32; ss++) ks += sK[ss * 64 + t];
    }
    #pragma unroll 4
    for (int ss = 0; ss < 32; ss++) {
      const float vm = sV[ss * 64 + m];
      const float* kr = sK + ss * 64 + dg;
      #pragma unroll
      for (int j = 0; j < 16; j++) acc[j] += kr[j] * vm;
    }
  }

  const int bh = b * NHH + h;
  float* kvp = kvpart + (size_t)(bh * KVSPLIT + sp) * 4096 + m * 64 + dg;
  #pragma unroll
  for (int j = 0; j < 16; j += 4) {
    f32x4 o;
    o[0] = acc[j]; o[1] = acc[j+1]; o[2] = acc[j+2]; o[3] = acc[j+3];
    *(f32x4*)(kvp + j) = o;
  }
  if (t < 64) kspart[(bh * KVSPLIT + sp) * 64 + t] = ks;
}

// ---------------- reduce partials -> kv bf16 [bh][m][d], ksum fp32 ----------------
__global__ __launch_bounds__(256) void kv_reduce_kernel(
    const float* __restrict__ kvpart, const float* __restrict__ kspart,
    short* __restrict__ kvbf, float* __restrict__ ksum)
{
  const int bh = blockIdx.x;
  const int t = threadIdx.x;
  const float* src = kvpart + (size_t)bh * KVSPLIT * 4096;
  #pragma unroll
  for (int i = 0; i < 4; i++) {
    const int idx = t + i * 256;  // f32x4 index within 4096
    f32x4 s = {};
    #pragma unroll 4
    for (int p = 0; p < KVSPLIT; p++)
      s += ((const f32x4*)(src + (size_t)p * 4096))[idx];
    short4 o;
    o.x = f2bf(s[0]); o.y = f2bf(s[1]); o.z = f2bf(s[2]); o.w = f2bf(s[3]);
    ((short4*)(kvbf + (size_t)bh * 4096))[idx] = o;
  }
  if (t < 64) {
    float s = 0.f;
    #pragma unroll
    for (int p = 0; p < KVSPLIT; p++) s += kspart[(bh * KVSPLIT + p) * 64 + t];
    ksum[bh * 64 + t] = s + 1e-6f;
  }
}

// ---------------- ctx via MFMA: per (b,h), ctx = diag(z) . Q[4096x64] @ kv[64x64]^T ----------------
__global__ __launch_bounds__(256) void ctx_mfma(
    const short* __restrict__ Q, const short* __restrict__ kvbf,
    const float* __restrict__ ksum, short* __restrict__ ctx)
{
  __shared__ __align__(16) short sB[64 * 72];
  __shared__ float sks[64];
  __shared__ float sz[256];
  const int b = blockIdx.z, h = blockIdx.y;
  const int t = threadIdx.x;
  const int lane = t & 63, wave = t >> 6;
  const int s0 = blockIdx.x * 256;
  const int bh = b * NHH + h;

  { // stage kv -> LDS (padded)
    const short8_t* src = (const short8_t*)(kvbf + (size_t)bh * 4096);
    const int m = t >> 2, c = (t & 3) * 16;
    short8_t v0 = src[t * 2], v1 = src[t * 2 + 1];
    *(short8_t*)(sB + m * 72 + c)     = v0;
    *(short8_t*)(sB + m * 72 + c + 8) = v1;
  }
  if (t < 64) sks[t] = ksum[bh * 64 + t];
  __syncthreads();

  { // per-token normalizer z = 1/(q . ksum)
    const short* qp = Q + (size_t)(b * SS + s0 + t) * HH + h * HDD;
    float zden = 0.f;
    #pragma unroll
    for (int i = 0; i < 8; i++) {
      short8_t q8 = *(const short8_t*)(qp + i * 8);
      #pragma unroll
      for (int j = 0; j < 8; j++) zden += bf2f(q8[j]) * sks[i * 8 + j];
    }
    sz[t] = 1.f / zden;
  }
  __syncthreads();

  const int fr = lane & 15, fk = (lane >> 4) * 8;
  const int wrow = wave * 64;
  f32x4 acc[4][4] = {};
  const short* qbase = Q + (size_t)(b * SS + s0 + wrow + fr) * HH + h * HDD + fk;
  #pragma unroll
  for (int k0 = 0; k0 < 64; k0 += 32) {
    short8_t af[4], wf[4];
    #pragma unroll
    for (int i = 0; i < 4; i++)
      af[i] = *(const short8_t*)(qbase + (size_t)(i * 16) * HH + k0);
    #pragma unroll
    for (int j = 0; j < 4; j++)
      wf[j] = *(const short8_t*)(sB + (j * 16 + fr) * 72 + fk + k0);
    #pragma unroll
    for (int i = 0; i < 4; i++) {
      #pragma unroll
      for (int j = 0; j < 4; j++) {
        acc[i][j] = __builtin_amdgcn_mfma_f32_16x16x32_bf16(af[i], wf[j], acc[i][j], 0, 0, 0);
      }
    }
  }

  const int cr = (lane >> 4) * 4, cc = lane & 15;
  short* cp = ctx + ((size_t)(b * SS + s0)) * HH + h * HDD;
  #pragma unroll
  for (int j = 0; j < 4; j++) {
    const int col = j * 16 + cc;
    #pragma unroll
    for (int i = 0; i < 4; i++) {
      #pragma unroll
      for (int r = 0; r < 4; r++) {
        const int row = wrow + i * 16 + cr + r;
        cp[(size_t)row * HH + col] = f2bf(acc[i][j][r] * sz[row]);
      }
    }
  }
}

// ---------------- LayerNorm(P + x) * gamma + beta ----------------
__global__ __launch_bounds__(256) void ln_kernel(
    const short* __restrict__ P, const float* __restrict__ x,
    const float* __restrict__ gamma, const float* __restrict__ beta,
    float* __restrict__ out)
{
  const int row = blockIdx.x;
  const int t = threadIdx.x;
  const short* pr = P + (size_t)row * HH;
  const float* xr = x + (size_t)row * HH;
  short4 p4 = ((const short4*)pr)[t];
  float4 x4 = ((const float4*)xr)[t];
  float h0 = bf2f(p4.x) + x4.x;
  float h1 = bf2f(p4.y) + x4.y;
  float h2 = bf2f(p4.z) + x4.z;
  float h3 = bf2f(p4.w) + x4.w;
  float s1 = h0 + h1 + h2 + h3;
  float s2 = h0*h0 + h1*h1 + h2*h2 + h3*h3;
  #pragma unroll
  for (int o = 32; o > 0; o >>= 1) {
    s1 += __shfl_xor(s1, o);
    s2 += __shfl_xor(s2, o);
  }
  __shared__ float red[8];
  const int wv = t >> 6, ln = t & 63;
  if (ln == 0) { red[wv] = s1; red[4 + wv] = s2; }
  __syncthreads();
  const float S1 = red[0] + red[1] + red[2] + red[3];
  const float S2 = red[4] + red[5] + red[6] + red[7];
  const float mu  = S1 * (1.f / HH);
  const float var = S2 * (1.f / HH) - mu * mu;
  const float inv = rsqrtf(var + 1e-12f);
  float4 g4 = ((const float4*)gamma)[t];
  float4 b4 = ((const float4*)beta)[t];
  float4 o4;
  o4.x = (h0 - mu) * inv * g4.x + b4.x;
  o4.y = (h1 - mu) * inv * g4.y + b4.y;
  o4.z = (h2 - mu) * inv * g4.z + b4.z;
  o4.w = (h3 - mu) * inv * g4.w + b4.w;
  ((float4*)(out + (size_t)row * HH))[t] = o4;
}

extern "C" void kernel_launch(void* const* d_in, const int* in_sizes, int n_in,
                              void* d_out, int out_size, void* d_ws, size_t ws_size,
                              hipStream_t stream)
{
  const float* x     = (const float*)d_in[0];
  // d_in[1] = attention_mask: unused (all zeros; reference ignores it)
  const float* Wq    = (const float*)d_in[2];
  const float* bq    = (const float*)d_in[3];
  const float* Wk    = (const float*)d_in[4];
  const float* bk    = (const float*)d_in[5];
  const float* Wv    = (const float*)d_in[6];
  const float* bv    = (const float*)d_in[7];
  const float* Wd    = (const float*)d_in[8];
  const float* bd    = (const float*)d_in[9];
  const float* gamma = (const float*)d_in[10];
  const float* beta  = (const float*)d_in[11];
  float* out = (float*)d_out;

  char* ws = (char*)d_ws;
  const size_t MB64 = 67108864;
  short* xb  = (short*)(ws + 0 * MB64);
  short* Qb  = (short*)(ws + 1 * MB64);
  short* Kb  = (short*)(ws + 2 * MB64);
  short* Vb  = (short*)(ws + 3 * MB64);
  short* Cb  = (short*)(ws + 4 * MB64);
  short* Wqb = (short*)(ws + 5 * MB64 + 0 * 2097152);
  short* Wkb = (short*)(ws + 5 * MB64 + 1 * 2097152);
  short* Wvb = (short*)(ws + 5 * MB64 + 2 * 2097152);
  short* Wdb = (short*)(ws + 5 * MB64 + 3 * 2097152);
  short* kvbf= (short*)(ws + 5 * MB64 + 4 * 2097152);
  float* ksb = (float*)(ws + 5 * MB64 + 5 * 2097152);
  // kv partials overlay Cb region (not live until ctx_mfma)
  float* kvpart = (float*)(ws + 4 * MB64);
  float* kspart = kvpart + (size_t)128 * KVSPLIT * 4096;
  short* Pb  = Qb;  // Q dead after ctx_mfma

  cvt_bf16<<<(MM * HH / 4) / 256, 256, 0, stream>>>(x,  xb,  MM * HH / 4);
  cvt_bf16<<<(HH * HH / 4) / 256, 256, 0, stream>>>(Wq, Wqb, HH * HH / 4);
  cvt_bf16<<<(HH * HH / 4) / 256, 256, 0, stream>>>(Wk, Wkb, HH * HH / 4);
  cvt_bf16<<<(HH * HH / 4) / 256, 256, 0, stream>>>(Wv, Wvb, HH * HH / 4);
  cvt_bf16<<<(HH * HH / 4) / 256, 256, 0, stream>>>(Wd, Wdb, HH * HH / 4);

  qkv_gemm<<<dim3(12, MM / BMt), 512, 0, stream>>>(xb, Wqb, Wkb, Wvb, bq, bk, bv, Qb, Kb, Vb);

  kv_part_kernel<<<dim3(NHH, BB, KVSPLIT), 256, 0, stream>>>(Kb, Vb, kvpart, kspart);
  kv_reduce_kernel<<<BB * NHH, 256, 0, stream>>>(kvpart, kspart, kvbf, ksb);
  ctx_mfma<<<dim3(SS / 256, NHH, BB), 256, 0, stream>>>(Qb, kvbf, ksb, Cb);

  dproj_gemm<<<dim3(HH / BNt, MM / BMt), 512, 0, stream>>>(Cb, Wdb, bd, Pb);
  ln_kernel<<<MM, 256, 0, stream>>>(Pb, x, gamma, beta, out);
}

// Round 4
// 721.190 us; speedup vs baseline: 1.3055x; 1.0450x over previous
//
#include <hip/hip_runtime.h>
#include <cstdint>
#include <cstddef>

#define BB 8
#define SS 4096
#define HH 1024
#define NHH 16
#define HDD 64
#define MM (BB*SS)   // 32768
#define KVSPLIT 16

#define BMt 256
#define BNt 256
#define BKt 64
#define NTt (HH/BKt)  // 16

typedef __attribute__((ext_vector_type(8))) short short8_t;
typedef __attribute__((ext_vector_type(4))) float f32x4;

__device__ __forceinline__ float bf2f(short u) {
  unsigned int x = ((unsigned int)(unsigned short)u) << 16;
  return __uint_as_float(x);
}
__device__ __forceinline__ short f2bf(float f) {
  unsigned int u = __float_as_uint(f);
  u += 0x7FFFu + ((u >> 16) & 1u);
  return (short)(u >> 16);
}

__device__ __forceinline__ void gload_lds16(const void* g, void* l) {
  __builtin_amdgcn_global_load_lds(
      (const __attribute__((address_space(1))) void*)g,
      (__attribute__((address_space(3))) void*)l, 16, 0, 0);
}

// ---------------- fp32 -> bf16 convert (vectorized) ----------------
__global__ void cvt_bf16(const float* __restrict__ in, short* __restrict__ out, int n4) {
  int i = blockIdx.x * blockDim.x + threadIdx.x;
  if (i >= n4) return;
  float4 v = ((const float4*)in)[i];
  short4 o;
  o.x = f2bf(v.x); o.y = f2bf(v.y); o.z = f2bf(v.z); o.w = f2bf(v.w);
  ((short4*)out)[i] = o;
}

// ---------------- 256x256 counted-vmcnt GEMM body: C = act(A @ W^T + bias) ----------------
// 512 threads / 8 waves. Phase-rotated row halves: p0/p1 compute C rows 0-127
// (ks0/ks1), p2/p3 rows 128-255. Waves = 2(row-quarter) x 4(64-col). A(t)h0 dead
// after p1, A(t)h1 after p3, B(t) after p1 (B-frags register-resident) -> per-phase
// half-tile staging rota 5-6 phases ahead:
//   p0: A(t+1)h1 | p2: A(t+2)h0 + B(t+2)h0 | p3: B(t+2)h1
// waits: vmcnt(8) at end-p1 / end-p3 ONLY (8 loads stay in flight across barriers);
// vmcnt(0) only in last 2 tail iterations. (slot ^ row&7) LDS swizzle, inverse-
// swizzled global source. Count algebra verified prologue->iter0->steady->tail.
__device__ __forceinline__ void gemm256_body(
    const short* __restrict__ A, const short* __restrict__ W,
    const float* __restrict__ bias, short* __restrict__ C,
    int m0, int n0, bool act)
{
  __shared__ __align__(16) char smem[131072];  // [A: 2x32KB][B: 2x32KB]

  const int tid  = threadIdx.x;
  const int lane = tid & 63;
  const int wm2  = (tid >> 6) >> 2;   // 0..1 row-quarter within active half
  const int wn   = (tid >> 6) & 3;    // 0..3 64-col group
  const int fr   = lane & 15;
  const int fg   = lane >> 4;         // 0..3

  // staging: unit = 64 rows x 64 shorts (8KB); thread -> (row=tid>>3, slot=tid&7)
  const int urow  = tid >> 3;
  const int uslot = tid & 7;
  const short* Asrc = A + (size_t)(m0 + urow) * HH + ((uslot ^ (urow & 7)) << 3);
  const short* Bsrc = W + (size_t)(n0 + urow) * HH + ((uslot ^ (urow & 7)) << 3);
  char* Adst = smem + tid * 16;            // linear LDS dest
  char* Bdst = smem + 65536 + tid * 16;

  // half h = rows [h*128, h*128+128) = units 2h, 2h+1 (2 gload instrs per wave)
#define STG_AH(b, kt, h) do { \
    gload_lds16(Asrc + (size_t)((h)*2+0) * 64 * HH + (kt) * 64, Adst + (b) * 32768 + ((h)*2+0) * 8192); \
    gload_lds16(Asrc + (size_t)((h)*2+1) * 64 * HH + (kt) * 64, Adst + (b) * 32768 + ((h)*2+1) * 8192); \
  } while (0)
#define STG_BH(b, kt, h) do { \
    gload_lds16(Bsrc + (size_t)((h)*2+0) * 64 * HH + (kt) * 64, Bdst + (b) * 32768 + ((h)*2+0) * 8192); \
    gload_lds16(Bsrc + (size_t)((h)*2+1) * 64 * HH + (kt) * 64, Bdst + (b) * 32768 + ((h)*2+1) * 8192); \
  } while (0)

  // ds_read bases: LDS byte = buf*32768 + row*128 + (slot ^ (row&7))*16
  const char* pA = smem + fr * 128;
  const char* pB = smem + 65536 + (wn * 64 + fr) * 128;
  const int sw0 = ((fg)     ^ (fr & 7)) << 4;   // k-slice 0 slots 0..3
  const int sw1 = ((4 + fg) ^ (fr & 7)) << 4;   // k-slice 1 slots 4..7
  const int rowA = wm2 * 8192;                  // wave's 64-row quarter within half

  f32x4 acc[8][4] = {};
  short8_t bfrag[2][4];

  // ---- prologue: 14 loads in exact issue order, wait vmcnt(8) ----
  STG_AH(0, 0, 0);   // A(0)h0
  STG_BH(0, 0, 0);   // B(0)h0
  STG_BH(0, 0, 1);   // B(0)h1
  STG_AH(0, 0, 1);   // A(0)h1   (stays in flight; drained by iter0 end-p1)
  STG_AH(1, 1, 0);   // A(1)h0
  STG_BH(1, 1, 0);   // B(1)h0
  STG_BH(1, 1, 1);   // B(1)h1
  asm volatile("s_waitcnt vmcnt(8)" ::: "memory");
  __builtin_amdgcn_s_barrier();
  __builtin_amdgcn_sched_barrier(0);

  #pragma unroll 2
  for (int kt = 0; kt < NTt; ++kt) {
    const int buf = kt & 1;
    const int ao = buf * 32768;
    short8_t af[4];

    // ---- p0: half0, ks0 (+ stage A(t+1)h1) ----
    #pragma unroll
    for (int j = 0; j < 4; j++) bfrag[0][j] = *(const short8_t*)(pB + ao + j * 2048 + sw0);
    #pragma unroll
    for (int i = 0; i < 4; i++) af[i] = *(const short8_t*)(pA + ao + rowA + i * 2048 + sw0);
    if (kt + 1 < NTt) STG_AH(buf ^ 1, kt + 1, 1);
    __builtin_amdgcn_s_barrier();
    __builtin_amdgcn_sched_barrier(0);
    __builtin_amdgcn_s_setprio(1);
    #pragma unroll
    for (int i = 0; i < 4; i++)
      #pragma unroll
      for (int j = 0; j < 4; j++)
        acc[i][j] = __builtin_amdgcn_mfma_f32_16x16x32_bf16(af[i], bfrag[0][j], acc[i][j], 0, 0, 0);
    __builtin_amdgcn_s_setprio(0);
    __builtin_amdgcn_s_barrier();
    __builtin_amdgcn_sched_barrier(0);

    // ---- p1: half0, ks1 ----
    #pragma unroll
    for (int j = 0; j < 4; j++) bfrag[1][j] = *(const short8_t*)(pB + ao + j * 2048 + sw1);
    #pragma unroll
    for (int i = 0; i < 4; i++) af[i] = *(const short8_t*)(pA + ao + rowA + i * 2048 + sw1);
    __builtin_amdgcn_s_barrier();
    __builtin_amdgcn_sched_barrier(0);
    __builtin_amdgcn_s_setprio(1);
    #pragma unroll
    for (int i = 0; i < 4; i++)
      #pragma unroll
      for (int j = 0; j < 4; j++)
        acc[i][j] = __builtin_amdgcn_mfma_f32_16x16x32_bf16(af[i], bfrag[1][j], acc[i][j], 0, 0, 0);
    __builtin_amdgcn_s_setprio(0);
    // counted drain: exactly frees A(t)h1 (needed at p2); 8 loads stay in flight
    if (kt < NTt - 2) asm volatile("s_waitcnt vmcnt(8)" ::: "memory");
    else              asm volatile("s_waitcnt vmcnt(0)" ::: "memory");
    __builtin_amdgcn_s_barrier();
    __builtin_amdgcn_sched_barrier(0);

    // ---- p2: half1, ks0 (+ stage A(t+2)h0, B(t+2)h0 into freed regions) ----
    #pragma unroll
    for (int i = 0; i < 4; i++) af[i] = *(const short8_t*)(pA + ao + 16384 + rowA + i * 2048 + sw0);
    if (kt + 2 < NTt) { STG_AH(buf, kt + 2, 0); STG_BH(buf, kt + 2, 0); }
    __builtin_amdgcn_s_barrier();
    __builtin_amdgcn_sched_barrier(0);
    __builtin_amdgcn_s_setprio(1);
    #pragma unroll
    for (int i = 0; i < 4; i++)
      #pragma unroll
      for (int j = 0; j < 4; j++)
        acc[4 + i][j] = __builtin_amdgcn_mfma_f32_16x16x32_bf16(af[i], bfrag[0][j], acc[4 + i][j], 0, 0, 0);
    __builtin_amdgcn_s_setprio(0);
    __builtin_amdgcn_s_barrier();
    __builtin_amdgcn_sched_barrier(0);

    // ---- p3: half1, ks1 (+ stage B(t+2)h1) ----
    #pragma unroll
    for (int i = 0; i < 4; i++) af[i] = *(const short8_t*)(pA + ao + 16384 + rowA + i * 2048 + sw1);
    if (kt + 2 < NTt) STG_BH(buf, kt + 2, 1);
    __builtin_amdgcn_s_barrier();
    __builtin_amdgcn_sched_barrier(0);
    __builtin_amdgcn_s_setprio(1);
    #pragma unroll
    for (int i = 0; i < 4; i++)
      #pragma unroll
      for (int j = 0; j < 4; j++)
        acc[4 + i][j] = __builtin_amdgcn_mfma_f32_16x16x32_bf16(af[i], bfrag[1][j], acc[4 + i][j], 0, 0, 0);
    __builtin_amdgcn_s_setprio(0);
    // counted drain: frees tile t+1's remaining halves (needed at next p0)
    if (kt < NTt - 2) asm volatile("s_waitcnt vmcnt(8)" ::: "memory");
    else              asm volatile("s_waitcnt vmcnt(0)" ::: "memory");
    __builtin_amdgcn_s_barrier();
    __builtin_amdgcn_sched_barrier(0);
  }
#undef STG_AH
#undef STG_BH

  // ---- epilogue: bias+act, two-pass LDS transpose (stride 264), short8 stores ----
  // all 8 waves participate in both half-passes (each wave owns rows in both halves)
  short* sC = (short*)smem;   // 128 x 264 x 2B = 67584 B
  float bvj[4];
  #pragma unroll
  for (int j = 0; j < 4; j++) bvj[j] = bias[n0 + wn * 64 + j * 16 + fr];

  #pragma unroll
  for (int h = 0; h < 2; ++h) {
    #pragma unroll
    for (int i = 0; i < 4; i++) {
      #pragma unroll
      for (int j = 0; j < 4; j++) {
        const int col = wn * 64 + j * 16 + fr;
        #pragma unroll
        for (int r = 0; r < 4; r++) {
          float v = acc[h * 4 + i][j][r] + bvj[j];
          if (act) v = (v > 0.f) ? (v + 1.f) : __expf(v);
          sC[(wm2 * 64 + i * 16 + fg * 4 + r) * 264 + col] = f2bf(v);
        }
      }
    }
    __syncthreads();
    const int crow = tid >> 5;          // 0..15
    const int cch  = (tid & 31) * 8;    // short offset, 32 x 16B = 512B row
    #pragma unroll
    for (int p = 0; p < 8; p++) {
      const int row = p * 16 + crow;
      *(short8_t*)(C + (size_t)(m0 + h * 128 + row) * HH + n0 + cch) =
          *(const short8_t*)(sC + row * 264 + cch);
    }
    __syncthreads();
  }
}

// fused QKV: blockIdx.x = which*4 + ncol; consecutive x-blocks share the A tile (L2 reuse)
__global__ __launch_bounds__(512, 2) void qkv_gemm(
    const short* __restrict__ xb,
    const short* __restrict__ Wqb, const short* __restrict__ Wkb, const short* __restrict__ Wvb,
    const float* __restrict__ bq, const float* __restrict__ bk, const float* __restrict__ bv,
    short* __restrict__ Qo, short* __restrict__ Ko, short* __restrict__ Vo)
{
  const int which = blockIdx.x >> 2;
  const int n0 = (blockIdx.x & 3) * BNt;
  const int m0 = blockIdx.y * BMt;
  const short* W  = (which == 0) ? Wqb : (which == 1) ? Wkb : Wvb;
  const float* bs = (which == 0) ? bq  : (which == 1) ? bk  : bv;
  short* C        = (which == 0) ? Qo  : (which == 1) ? Ko  : Vo;
  gemm256_body(xb, W, bs, C, m0, n0, which < 2);
}

__global__ __launch_bounds__(512, 2) void dproj_gemm(
    const short* __restrict__ A, const short* __restrict__ W,
    const float* __restrict__ bias, short* __restrict__ C)
{
  gemm256_body(A, W, bias, C, blockIdx.y * BMt, blockIdx.x * BNt, false);
}

// ---------------- kv partials over S-splits ----------------
__global__ __launch_bounds__(256) void kv_part_kernel(
    const short* __restrict__ K_, const short* __restrict__ V_,
    float* __restrict__ kvpart, float* __restrict__ kspart)
{
  __shared__ __align__(16) float sK[32 * 64];
  __shared__ __align__(16) float sV[32 * 64];
  const int h = blockIdx.x, b = blockIdx.y, sp = blockIdx.z;
  const int t = threadIdx.x;
  const int m = t & 63;
  const int dg = (t >> 6) * 16;
  const int lrow = t >> 3;
  const int lcol = (t & 7) * 8;
  const int SC = SS / KVSPLIT;
  float acc[16] = {};
  float ks = 0.f;
  const size_t base = ((size_t)b * SS + (size_t)sp * SC) * HH + (size_t)h * HDD;
  const short* Kp = K_ + base + (size_t)lrow * HH + lcol;
  const short* Vp = V_ + base + (size_t)lrow * HH + lcol;

  for (int sc = 0; sc < SC; sc += 32) {
    short8_t k8 = *(const short8_t*)(Kp + (size_t)sc * HH);
    short8_t v8 = *(const short8_t*)(Vp + (size_t)sc * HH);
    __syncthreads();
    #pragma unroll
    for (int j = 0; j < 8; j++) {
      sK[lrow * 64 + lcol + j] = bf2f(k8[j]);
      sV[lrow * 64 + lcol + j] = bf2f(v8[j]);
    }
    __syncthreads();
    if (t < 64) {
      #pragma unroll
      for (int ss = 0; ss < 32; ss++) ks += sK[ss * 64 + t];
    }
    #pragma unroll 4
    for (int ss = 0; ss < 32; ss++) {
      const float vm = sV[ss * 64 + m];
      const float* kr = sK + ss * 64 + dg;
      #pragma unroll
      for (int j = 0; j < 16; j++) acc[j] += kr[j] * vm;
    }
  }

  const int bh = b * NHH + h;
  float* kvp = kvpart + (size_t)(bh * KVSPLIT + sp) * 4096 + m * 64 + dg;
  #pragma unroll
  for (int j = 0; j < 16; j += 4) {
    f32x4 o;
    o[0] = acc[j]; o[1] = acc[j+1]; o[2] = acc[j+2]; o[3] = acc[j+3];
    *(f32x4*)(kvp + j) = o;
  }
  if (t < 64) kspart[(bh * KVSPLIT + sp) * 64 + t] = ks;
}

// ---------------- reduce partials -> kv bf16 [bh][m][d], ksum fp32 ----------------
__global__ __launch_bounds__(256) void kv_reduce_kernel(
    const float* __restrict__ kvpart, const float* __restrict__ kspart,
    short* __restrict__ kvbf, float* __restrict__ ksum)
{
  const int bh = blockIdx.x;
  const int t = threadIdx.x;
  const float* src = kvpart + (size_t)bh * KVSPLIT * 4096;
  #pragma unroll
  for (int i = 0; i < 4; i++) {
    const int idx = t + i * 256;  // f32x4 index within 4096
    f32x4 s = {};
    #pragma unroll 4
    for (int p = 0; p < KVSPLIT; p++)
      s += ((const f32x4*)(src + (size_t)p * 4096))[idx];
    short4 o;
    o.x = f2bf(s[0]); o.y = f2bf(s[1]); o.z = f2bf(s[2]); o.w = f2bf(s[3]);
    ((short4*)(kvbf + (size_t)bh * 4096))[idx] = o;
  }
  if (t < 64) {
    float s = 0.f;
    #pragma unroll
    for (int p = 0; p < KVSPLIT; p++) s += kspart[(bh * KVSPLIT + p) * 64 + t];
    ksum[bh * 64 + t] = s + 1e-6f;
  }
}

// ---------------- ctx via MFMA: per (b,h), ctx = diag(z) . Q[4096x64] @ kv[64x64]^T ----------------
__global__ __launch_bounds__(256) void ctx_mfma(
    const short* __restrict__ Q, const short* __restrict__ kvbf,
    const float* __restrict__ ksum, short* __restrict__ ctx)
{
  __shared__ __align__(16) short sB[64 * 72];
  __shared__ float sks[64];
  __shared__ float sz[256];
  const int b = blockIdx.z, h = blockIdx.y;
  const int t = threadIdx.x;
  const int lane = t & 63, wave = t >> 6;
  const int s0 = blockIdx.x * 256;
  const int bh = b * NHH + h;

  { // stage kv -> LDS (padded)
    const short8_t* src = (const short8_t*)(kvbf + (size_t)bh * 4096);
    const int m = t >> 2, c = (t & 3) * 16;
    short8_t v0 = src[t * 2], v1 = src[t * 2 + 1];
    *(short8_t*)(sB + m * 72 + c)     = v0;
    *(short8_t*)(sB + m * 72 + c + 8) = v1;
  }
  if (t < 64) sks[t] = ksum[bh * 64 + t];
  __syncthreads();

  { // per-token normalizer z = 1/(q . ksum)
    const short* qp = Q + (size_t)(b * SS + s0 + t) * HH + h * HDD;
    float zden = 0.f;
    #pragma unroll
    for (int i = 0; i < 8; i++) {
      short8_t q8 = *(const short8_t*)(qp + i * 8);
      #pragma unroll
      for (int j = 0; j < 8; j++) zden += bf2f(q8[j]) * sks[i * 8 + j];
    }
    sz[t] = 1.f / zden;
  }
  __syncthreads();

  const int fr = lane & 15, fk = (lane >> 4) * 8;
  const int wrow = wave * 64;
  f32x4 acc[4][4] = {};
  const short* qbase = Q + (size_t)(b * SS + s0 + wrow + fr) * HH + h * HDD + fk;
  #pragma unroll
  for (int k0 = 0; k0 < 64; k0 += 32) {
    short8_t af[4], wf[4];
    #pragma unroll
    for (int i = 0; i < 4; i++)
      af[i] = *(const short8_t*)(qbase + (size_t)(i * 16) * HH + k0);
    #pragma unroll
    for (int j = 0; j < 4; j++)
      wf[j] = *(const short8_t*)(sB + (j * 16 + fr) * 72 + fk + k0);
    #pragma unroll
    for (int i = 0; i < 4; i++) {
      #pragma unroll
      for (int j = 0; j < 4; j++) {
        acc[i][j] = __builtin_amdgcn_mfma_f32_16x16x32_bf16(af[i], wf[j], acc[i][j], 0, 0, 0);
      }
    }
  }

  const int cr = (lane >> 4) * 4, cc = lane & 15;
  short* cp = ctx + ((size_t)(b * SS + s0)) * HH + h * HDD;
  #pragma unroll
  for (int j = 0; j < 4; j++) {
    const int col = j * 16 + cc;
    #pragma unroll
    for (int i = 0; i < 4; i++) {
      #pragma unroll
      for (int r = 0; r < 4; r++) {
        const int row = wrow + i * 16 + cr + r;
        cp[(size_t)row * HH + col] = f2bf(acc[i][j][r] * sz[row]);
      }
    }
  }
}

// ---------------- LayerNorm(P + x) * gamma + beta ----------------
__global__ __launch_bounds__(256) void ln_kernel(
    const short* __restrict__ P, const float* __restrict__ x,
    const float* __restrict__ gamma, const float* __restrict__ beta,
    float* __restrict__ out)
{
  const int row = blockIdx.x;
  const int t = threadIdx.x;
  const short* pr = P + (size_t)row * HH;
  const float* xr = x + (size_t)row * HH;
  short4 p4 = ((const short4*)pr)[t];
  float4 x4 = ((const float4*)xr)[t];
  float h0 = bf2f(p4.x) + x4.x;
  float h1 = bf2f(p4.y) + x4.y;
  float h2 = bf2f(p4.z) + x4.z;
  float h3 = bf2f(p4.w) + x4.w;
  float s1 = h0 + h1 + h2 + h3;
  float s2 = h0*h0 + h1*h1 + h2*h2 + h3*h3;
  #pragma unroll
  for (int o = 32; o > 0; o >>= 1) {
    s1 += __shfl_xor(s1, o);
    s2 += __shfl_xor(s2, o);
  }
  __shared__ float red[8];
  const int wv = t >> 6, ln = t & 63;
  if (ln == 0) { red[wv] = s1; red[4 + wv] = s2; }
  __syncthreads();
  const float S1 = red[0] + red[1] + red[2] + red[3];
  const float S2 = red[4] + red[5] + red[6] + red[7];
  const float mu  = S1 * (1.f / HH);
  const float var = S2 * (1.f / HH) - mu * mu;
  const float inv = rsqrtf(var + 1e-12f);
  float4 g4 = ((const float4*)gamma)[t];
  float4 b4 = ((const float4*)beta)[t];
  float4 o4;
  o4.x = (h0 - mu) * inv * g4.x + b4.x;
  o4.y = (h1 - mu) * inv * g4.y + b4.y;
  o4.z = (h2 - mu) * inv * g4.z + b4.z;
  o4.w = (h3 - mu) * inv * g4.w + b4.w;
  ((float4*)(out + (size_t)row * HH))[t] = o4;
}

extern "C" void kernel_launch(void* const* d_in, const int* in_sizes, int n_in,
                              void* d_out, int out_size, void* d_ws, size_t ws_size,
                              hipStream_t stream)
{
  const float* x     = (const float*)d_in[0];
  // d_in[1] = attention_mask: unused (all zeros; reference ignores it)
  const float* Wq    = (const float*)d_in[2];
  const float* bq    = (const float*)d_in[3];
  const float* Wk    = (const float*)d_in[4];
  const float* bk    = (const float*)d_in[5];
  const float* Wv    = (const float*)d_in[6];
  const float* bv    = (const float*)d_in[7];
  const float* Wd    = (const float*)d_in[8];
  const float* bd    = (const float*)d_in[9];
  const float* gamma = (const float*)d_in[10];
  const float* beta  = (const float*)d_in[11];
  float* out = (float*)d_out;

  char* ws = (char*)d_ws;
  const size_t MB64 = 67108864;
  short* xb  = (short*)(ws + 0 * MB64);
  short* Qb  = (short*)(ws + 1 * MB64);
  short* Kb  = (short*)(ws + 2 * MB64);
  short* Vb  = (short*)(ws + 3 * MB64);
  short* Cb  = (short*)(ws + 4 * MB64);
  short* Wqb = (short*)(ws + 5 * MB64 + 0 * 2097152);
  short* Wkb = (short*)(ws + 5 * MB64 + 1 * 2097152);
  short* Wvb = (short*)(ws + 5 * MB64 + 2 * 2097152);
  short* Wdb = (short*)(ws + 5 * MB64 + 3 * 2097152);
  short* kvbf= (short*)(ws + 5 * MB64 + 4 * 2097152);
  float* ksb = (float*)(ws + 5 * MB64 + 5 * 2097152);
  // kv partials overlay Cb region (not live until ctx_mfma)
  float* kvpart = (float*)(ws + 4 * MB64);
  float* kspart = kvpart + (size_t)128 * KVSPLIT * 4096;
  short* Pb  = Qb;  // Q dead after ctx_mfma

  cvt_bf16<<<(MM * HH / 4) / 256, 256, 0, stream>>>(x,  xb,  MM * HH / 4);
  cvt_bf16<<<(HH * HH / 4) / 256, 256, 0, stream>>>(Wq, Wqb, HH * HH / 4);
  cvt_bf16<<<(HH * HH / 4) / 256, 256, 0, stream>>>(Wk, Wkb, HH * HH / 4);
  cvt_bf16<<<(HH * HH / 4) / 256, 256, 0, stream>>>(Wv, Wvb, HH * HH / 4);
  cvt_bf16<<<(HH * HH / 4) / 256, 256, 0, stream>>>(Wd, Wdb, HH * HH / 4);

  qkv_gemm<<<dim3(12, MM / BMt), 512, 0, stream>>>(xb, Wqb, Wkb, Wvb, bq, bk, bv, Qb, Kb, Vb);

  kv_part_kernel<<<dim3(NHH, BB, KVSPLIT), 256, 0, stream>>>(Kb, Vb, kvpart, kspart);
  kv_reduce_kernel<<<BB * NHH, 256, 0, stream>>>(kvpart, kspart, kvbf, ksb);
  ctx_mfma<<<dim3(SS / 256, NHH, BB), 256, 0, stream>>>(Qb, kvbf, ksb, Cb);

  dproj_gemm<<<dim3(HH / BNt, MM / BMt), 512, 0, stream>>>(Cb, Wdb, bd, Pb);
  ln_kernel<<<MM, 256, 0, stream>>>(Pb, x, gamma, beta, out);
}

// Round 5
// 710.691 us; speedup vs baseline: 1.3247x; 1.0148x over previous
//
#include <hip/hip_runtime.h>
#include <cstdint>
#include <cstddef>

#define BB 8
#define SS 4096
#define HH 1024
#define NHH 16
#define HDD 64
#define MM (BB*SS)   // 32768
#define KVSPLIT 16

#define BMt 256
#define BNt 256
#define BKt 64
#define NTt (HH/BKt)  // 16

typedef __attribute__((ext_vector_type(8))) short short8_t;
typedef __attribute__((ext_vector_type(4))) float f32x4;

__device__ __forceinline__ float bf2f(short u) {
  unsigned int x = ((unsigned int)(unsigned short)u) << 16;
  return __uint_as_float(x);
}
__device__ __forceinline__ short f2bf(float f) {
  unsigned int u = __float_as_uint(f);
  u += 0x7FFFu + ((u >> 16) & 1u);
  return (short)(u >> 16);
}

__device__ __forceinline__ void gload_lds16(const void* g, void* l) {
  __builtin_amdgcn_global_load_lds(
      (const __attribute__((address_space(1))) void*)g,
      (__attribute__((address_space(3))) void*)l, 16, 0, 0);
}

// ---------------- fp32 -> bf16 convert (vectorized) ----------------
__global__ void cvt_bf16(const float* __restrict__ in, short* __restrict__ out, int n4) {
  int i = blockIdx.x * blockDim.x + threadIdx.x;
  if (i >= n4) return;
  float4 v = ((const float4*)in)[i];
  short4 o;
  o.x = f2bf(v.x); o.y = f2bf(v.y); o.z = f2bf(v.z); o.w = f2bf(v.w);
  ((short4*)out)[i] = o;
}

// ---------------- 256x256 read-ahead GEMM body: C = act(A @ W^T + bias) ----------------
// 512 threads / 8 waves (2 row-quarter x 4 col). 4 phases/K-tile; phase p's
// fragment ds_reads are issued in phase p-1 (double-buffered RA/RB regs) and
// waited with COUNTED lgkmcnt(8/4) after the barrier -> LDS drain hides under
// the previous MFMA cluster (T4 applied to lgkm; was the 1800cy/K-tile stall).
// Staging rota (tile t): p0: A(t+1)h1 | p2: A(t+2)h0+B(t+2)h0 | p3: B(t+2)h1.
// vmcnt gates: G2=vmcnt(8) end-p0 (A(t)h1 resident for p1 reads), G1=vmcnt(6)
// end-p2 (tile t+1 h0+B resident for p3 next-tile reads). Tail peeled
// (vmcnt 8/2, then 0/0). 4 barriers/K-tile. Count algebra hand-verified
// prologue -> steady -> tail, incl. all WAR/RAW windows vs barrier placement.
__device__ __forceinline__ void gemm256_body(
    const short* __restrict__ A, const short* __restrict__ W,
    const float* __restrict__ bias, short* __restrict__ C,
    int m0, int n0, bool act)
{
  __shared__ __align__(16) char smem[131072];  // [A: 2x32KB][B: 2x32KB]

  const int tid  = threadIdx.x;
  const int lane = tid & 63;
  const int wm2  = (tid >> 6) >> 2;   // 0..1 row-quarter within active half
  const int wn   = (tid >> 6) & 3;    // 0..3 64-col group
  const int fr   = lane & 15;
  const int fg   = lane >> 4;         // 0..3

  // staging: unit = 64 rows x 64 shorts (8KB); thread -> (row=tid>>3, slot=tid&7)
  const int urow  = tid >> 3;
  const int uslot = tid & 7;
  const short* Asrc = A + (size_t)(m0 + urow) * HH + ((uslot ^ (urow & 7)) << 3);
  const short* Bsrc = W + (size_t)(n0 + urow) * HH + ((uslot ^ (urow & 7)) << 3);
  char* Adst = smem + tid * 16;            // linear LDS dest
  char* Bdst = smem + 65536 + tid * 16;

#define STG_AH(b, kt, h) do { \
    gload_lds16(Asrc + (size_t)((h)*2+0) * 64 * HH + (kt) * 64, Adst + (b) * 32768 + ((h)*2+0) * 8192); \
    gload_lds16(Asrc + (size_t)((h)*2+1) * 64 * HH + (kt) * 64, Adst + (b) * 32768 + ((h)*2+1) * 8192); \
  } while (0)
#define STG_BH(b, kt, h) do { \
    gload_lds16(Bsrc + (size_t)((h)*2+0) * 64 * HH + (kt) * 64, Bdst + (b) * 32768 + ((h)*2+0) * 8192); \
    gload_lds16(Bsrc + (size_t)((h)*2+1) * 64 * HH + (kt) * 64, Bdst + (b) * 32768 + ((h)*2+1) * 8192); \
  } while (0)

  // ds_read bases: LDS byte = buf*32768 + unit*8192 + (row&63)*128 + (slot^(row&7))*16
  const char* pA = smem + fr * 128;
  const char* pB = smem + 65536 + (wn * 64 + fr) * 128;
  const int sw0 = ((fg)     ^ (fr & 7)) << 4;   // k-slice 0 slots 0..3
  const int sw1 = ((4 + fg) ^ (fr & 7)) << 4;   // k-slice 1 slots 4..7
  const int rowA = wm2 * 8192;                  // wave's 64-row quarter within half

#define DSR_A(RA, OFS, SW) do { \
    _Pragma("unroll") \
    for (int i_ = 0; i_ < 4; i_++) (RA)[i_] = *(const short8_t*)(pA + (OFS) + i_ * 2048 + (SW)); \
  } while (0)
#define DSR_B(RB, OFS, SW) do { \
    _Pragma("unroll") \
    for (int j_ = 0; j_ < 4; j_++) (RB)[j_] = *(const short8_t*)(pB + (OFS) + j_ * 2048 + (SW)); \
  } while (0)
#define MFMA16(OFS, RA, RB) do { \
    _Pragma("unroll") \
    for (int i_ = 0; i_ < 4; i_++) { \
      _Pragma("unroll") \
      for (int j_ = 0; j_ < 4; j_++) \
        acc[(OFS) + i_][j_] = __builtin_amdgcn_mfma_f32_16x16x32_bf16((RA)[i_], (RB)[j_], acc[(OFS) + i_][j_], 0, 0, 0); \
    } \
  } while (0)
#define LGKM8() asm volatile("s_waitcnt lgkmcnt(8)" ::: "memory")
#define LGKM4() asm volatile("s_waitcnt lgkmcnt(4)" ::: "memory")
#define LGKM0() asm volatile("s_waitcnt lgkmcnt(0)" ::: "memory")
#define SBAR()  __builtin_amdgcn_s_barrier()
#define SCHED() __builtin_amdgcn_sched_barrier(0)
#define PRIO1() __builtin_amdgcn_s_setprio(1)
#define PRIO0() __builtin_amdgcn_s_setprio(0)

  f32x4 acc[8][4] = {};
  short8_t RA0[4], RA1[4], RB0[4], RB1[4];

  // ---- prologue: 14 staged loads; first 6 = tile0 {Ah0,Bh0,Bh1} (drain set) ----
  STG_AH(0, 0, 0); STG_BH(0, 0, 0); STG_BH(0, 0, 1);
  SCHED();  // pin group boundary: first-6 vs rest (vmcnt(8) drains exactly first 6)
  STG_AH(0, 0, 1); STG_AH(1, 1, 0); STG_BH(1, 1, 0); STG_BH(1, 1, 1);
  asm volatile("s_waitcnt vmcnt(8)" ::: "memory");
  SBAR(); SCHED();
  // pre-read tile0: RA0 <- A h0 ks0, RB0 <- B ks0 (buf 0)
  DSR_B(RB0, 0, sw0);
  DSR_A(RA0, rowA, sw0);

  #pragma unroll 2
  for (int kt = 0; kt < NTt - 2; ++kt) {
    const int ao = (kt & 1) * 32768;
    const int an = ao ^ 32768;
    // ---- p0: MFMA h0ks0; read-ahead RA1/RB1 <- h0ks1; stage A(t+1)h1 ----
    DSR_B(RB1, ao, sw1);
    DSR_A(RA1, ao + rowA, sw1);
    STG_AH((kt & 1) ^ 1, kt + 1, 1);
    LGKM8(); SCHED();
    PRIO1(); MFMA16(0, RA0, RB0); PRIO0();
    asm volatile("s_waitcnt vmcnt(8)" ::: "memory");  // G2: A(t)h1 resident
    SBAR(); SCHED();
    // ---- p1: MFMA h0ks1; read-ahead RA0 <- h1ks0 ----
    DSR_A(RA0, ao + 16384 + rowA, sw0);
    LGKM4(); SCHED();
    PRIO1(); MFMA16(0, RA1, RB1); PRIO0();
    SBAR(); SCHED();
    // ---- p2: MFMA h1ks0; read-ahead RA1 <- h1ks1; stage A(t+2)h0+B(t+2)h0 ----
    DSR_A(RA1, ao + 16384 + rowA, sw1);
    STG_AH(kt & 1, kt + 2, 0); STG_BH(kt & 1, kt + 2, 0);
    LGKM4(); SCHED();
    PRIO1(); MFMA16(4, RA0, RB0); PRIO0();
    asm volatile("s_waitcnt vmcnt(6)" ::: "memory");  // G1: tile t+1 h0+B resident
    SBAR(); SCHED();
    // ---- p3: MFMA h1ks1; read-ahead tile t+1: RA0/RB0 <- h0ks0 (buf^1); stage B(t+2)h1 ----
    DSR_B(RB0, an, sw0);
    DSR_A(RA0, an + rowA, sw0);
    STG_BH(kt & 1, kt + 2, 1);
    LGKM8(); SCHED();
    PRIO1(); MFMA16(4, RA1, RB1); PRIO0();
    SBAR(); SCHED();
  }

  // ---- peeled kt = NTt-2 (stages for tile NTt-1 h1 only; G1 -> vmcnt(2)) ----
  {
    const int ao = ((NTt - 2) & 1) * 32768;
    const int an = ao ^ 32768;
    DSR_B(RB1, ao, sw1);
    DSR_A(RA1, ao + rowA, sw1);
    STG_AH(((NTt - 2) & 1) ^ 1, NTt - 1, 1);
    LGKM8(); SCHED();
    PRIO1(); MFMA16(0, RA0, RB0); PRIO0();
    asm volatile("s_waitcnt vmcnt(8)" ::: "memory");
    SBAR(); SCHED();
    DSR_A(RA0, ao + 16384 + rowA, sw0);
    LGKM4(); SCHED();
    PRIO1(); MFMA16(0, RA1, RB1); PRIO0();
    SBAR(); SCHED();
    DSR_A(RA1, ao + 16384 + rowA, sw1);
    LGKM4(); SCHED();
    PRIO1(); MFMA16(4, RA0, RB0); PRIO0();
    asm volatile("s_waitcnt vmcnt(2)" ::: "memory");  // drains A/B(NTt-1)h0 + B h1
    SBAR(); SCHED();
    DSR_B(RB0, an, sw0);
    DSR_A(RA0, an + rowA, sw0);
    LGKM8(); SCHED();
    PRIO1(); MFMA16(4, RA1, RB1); PRIO0();
    SBAR(); SCHED();
  }
  // ---- peeled kt = NTt-1 (no staging; G2 -> vmcnt(0)) ----
  {
    const int ao = ((NTt - 1) & 1) * 32768;
    DSR_B(RB1, ao, sw1);
    DSR_A(RA1, ao + rowA, sw1);
    LGKM8(); SCHED();
    PRIO1(); MFMA16(0, RA0, RB0); PRIO0();
    asm volatile("s_waitcnt vmcnt(0)" ::: "memory");  // drains A(NTt-1)h1
    SBAR(); SCHED();
    DSR_A(RA0, ao + 16384 + rowA, sw0);
    LGKM4(); SCHED();
    PRIO1(); MFMA16(0, RA1, RB1); PRIO0();
    SBAR(); SCHED();
    DSR_A(RA1, ao + 16384 + rowA, sw1);
    LGKM4(); SCHED();
    PRIO1(); MFMA16(4, RA0, RB0); PRIO0();
    SBAR(); SCHED();
    LGKM0(); SCHED();
    PRIO1(); MFMA16(4, RA1, RB1); PRIO0();
    SBAR(); SCHED();
  }
#undef STG_AH
#undef STG_BH

  // ---- epilogue: bias+act, two-pass LDS transpose (stride 264), short8 stores ----
  short* sC = (short*)smem;   // 128 x 264 x 2B = 67584 B
  float bvj[4];
  #pragma unroll
  for (int j = 0; j < 4; j++) bvj[j] = bias[n0 + wn * 64 + j * 16 + fr];

  #pragma unroll
  for (int h = 0; h < 2; ++h) {
    #pragma unroll
    for (int i = 0; i < 4; i++) {
      #pragma unroll
      for (int j = 0; j < 4; j++) {
        const int col = wn * 64 + j * 16 + fr;
        #pragma unroll
        for (int r = 0; r < 4; r++) {
          float v = acc[h * 4 + i][j][r] + bvj[j];
          if (act) v = (v > 0.f) ? (v + 1.f) : __expf(v);
          sC[(wm2 * 64 + i * 16 + fg * 4 + r) * 264 + col] = f2bf(v);
        }
      }
    }
    __syncthreads();
    const int crow = tid >> 5;          // 0..15
    const int cch  = (tid & 31) * 8;    // short offset, 32 x 16B = 512B row
    #pragma unroll
    for (int p = 0; p < 8; p++) {
      const int row = p * 16 + crow;
      *(short8_t*)(C + (size_t)(m0 + h * 128 + row) * HH + n0 + cch) =
          *(const short8_t*)(sC + row * 264 + cch);
    }
    __syncthreads();
  }
#undef DSR_A
#undef DSR_B
#undef MFMA16
#undef LGKM8
#undef LGKM4
#undef LGKM0
#undef SBAR
#undef SCHED
#undef PRIO1
#undef PRIO0
}

// fused QKV: blockIdx.x = which*4 + ncol; consecutive x-blocks share the A tile (L2 reuse)
__global__ __launch_bounds__(512, 2) void qkv_gemm(
    const short* __restrict__ xb,
    const short* __restrict__ Wqb, const short* __restrict__ Wkb, const short* __restrict__ Wvb,
    const float* __restrict__ bq, const float* __restrict__ bk, const float* __restrict__ bv,
    short* __restrict__ Qo, short* __restrict__ Ko, short* __restrict__ Vo)
{
  const int which = blockIdx.x >> 2;
  const int n0 = (blockIdx.x & 3) * BNt;
  const int m0 = blockIdx.y * BMt;
  const short* W  = (which == 0) ? Wqb : (which == 1) ? Wkb : Wvb;
  const float* bs = (which == 0) ? bq  : (which == 1) ? bk  : bv;
  short* C        = (which == 0) ? Qo  : (which == 1) ? Ko  : Vo;
  gemm256_body(xb, W, bs, C, m0, n0, which < 2);
}

__global__ __launch_bounds__(512, 2) void dproj_gemm(
    const short* __restrict__ A, const short* __restrict__ W,
    const float* __restrict__ bias, short* __restrict__ C)
{
  gemm256_body(A, W, bias, C, blockIdx.y * BMt, blockIdx.x * BNt, false);
}

// ---------------- kv partials over S-splits ----------------
__global__ __launch_bounds__(256) void kv_part_kernel(
    const short* __restrict__ K_, const short* __restrict__ V_,
    float* __restrict__ kvpart, float* __restrict__ kspart)
{
  __shared__ __align__(16) float sK[32 * 64];
  __shared__ __align__(16) float sV[32 * 64];
  const int h = blockIdx.x, b = blockIdx.y, sp = blockIdx.z;
  const int t = threadIdx.x;
  const int m = t & 63;
  const int dg = (t >> 6) * 16;
  const int lrow = t >> 3;
  const int lcol = (t & 7) * 8;
  const int SC = SS / KVSPLIT;
  float acc[16] = {};
  float ks = 0.f;
  const size_t base = ((size_t)b * SS + (size_t)sp * SC) * HH + (size_t)h * HDD;
  const short* Kp = K_ + base + (size_t)lrow * HH + lcol;
  const short* Vp = V_ + base + (size_t)lrow * HH + lcol;

  for (int sc = 0; sc < SC; sc += 32) {
    short8_t k8 = *(const short8_t*)(Kp + (size_t)sc * HH);
    short8_t v8 = *(const short8_t*)(Vp + (size_t)sc * HH);
    __syncthreads();
    #pragma unroll
    for (int j = 0; j < 8; j++) {
      sK[lrow * 64 + lcol + j] = bf2f(k8[j]);
      sV[lrow * 64 + lcol + j] = bf2f(v8[j]);
    }
    __syncthreads();
    if (t < 64) {
      #pragma unroll
      for (int ss = 0; ss < 32; ss++) ks += sK[ss * 64 + t];
    }
    #pragma unroll 4
    for (int ss = 0; ss < 32; ss++) {
      const float vm = sV[ss * 64 + m];
      const float* kr = sK + ss * 64 + dg;
      #pragma unroll
      for (int j = 0; j < 16; j++) acc[j] += kr[j] * vm;
    }
  }

  const int bh = b * NHH + h;
  float* kvp = kvpart + (size_t)(bh * KVSPLIT + sp) * 4096 + m * 64 + dg;
  #pragma unroll
  for (int j = 0; j < 16; j += 4) {
    f32x4 o;
    o[0] = acc[j]; o[1] = acc[j+1]; o[2] = acc[j+2]; o[3] = acc[j+3];
    *(f32x4*)(kvp + j) = o;
  }
  if (t < 64) kspart[(bh * KVSPLIT + sp) * 64 + t] = ks;
}

// ---------------- reduce partials -> kv bf16 [bh][m][d], ksum fp32 ----------------
__global__ __launch_bounds__(256) void kv_reduce_kernel(
    const float* __restrict__ kvpart, const float* __restrict__ kspart,
    short* __restrict__ kvbf, float* __restrict__ ksum)
{
  const int bh = blockIdx.x;
  const int t = threadIdx.x;
  const float* src = kvpart + (size_t)bh * KVSPLIT * 4096;
  #pragma unroll
  for (int i = 0; i < 4; i++) {
    const int idx = t + i * 256;  // f32x4 index within 4096
    f32x4 s = {};
    #pragma unroll 4
    for (int p = 0; p < KVSPLIT; p++)
      s += ((const f32x4*)(src + (size_t)p * 4096))[idx];
    short4 o;
    o.x = f2bf(s[0]); o.y = f2bf(s[1]); o.z = f2bf(s[2]); o.w = f2bf(s[3]);
    ((short4*)(kvbf + (size_t)bh * 4096))[idx] = o;
  }
  if (t < 64) {
    float s = 0.f;
    #pragma unroll
    for (int p = 0; p < KVSPLIT; p++) s += kspart[(bh * KVSPLIT + p) * 64 + t];
    ksum[bh * 64 + t] = s + 1e-6f;
  }
}

// ---------------- ctx via MFMA: per (b,h), ctx = diag(z) . Q[4096x64] @ kv[64x64]^T ----------------
__global__ __launch_bounds__(256) void ctx_mfma(
    const short* __restrict__ Q, const short* __restrict__ kvbf,
    const float* __restrict__ ksum, short* __restrict__ ctx)
{
  __shared__ __align__(16) short sB[64 * 72];
  __shared__ float sks[64];
  __shared__ float sz[256];
  const int b = blockIdx.z, h = blockIdx.y;
  const int t = threadIdx.x;
  const int lane = t & 63, wave = t >> 6;
  const int s0 = blockIdx.x * 256;
  const int bh = b * NHH + h;

  { // stage kv -> LDS (padded)
    const short8_t* src = (const short8_t*)(kvbf + (size_t)bh * 4096);
    const int m = t >> 2, c = (t & 3) * 16;
    short8_t v0 = src[t * 2], v1 = src[t * 2 + 1];
    *(short8_t*)(sB + m * 72 + c)     = v0;
    *(short8_t*)(sB + m * 72 + c + 8) = v1;
  }
  if (t < 64) sks[t] = ksum[bh * 64 + t];
  __syncthreads();

  { // per-token normalizer z = 1/(q . ksum)
    const short* qp = Q + (size_t)(b * SS + s0 + t) * HH + h * HDD;
    float zden = 0.f;
    #pragma unroll
    for (int i = 0; i < 8; i++) {
      short8_t q8 = *(const short8_t*)(qp + i * 8);
      #pragma unroll
      for (int j = 0; j < 8; j++) zden += bf2f(q8[j]) * sks[i * 8 + j];
    }
    sz[t] = 1.f / zden;
  }
  __syncthreads();

  const int fr = lane & 15, fk = (lane >> 4) * 8;
  const int wrow = wave * 64;
  f32x4 acc[4][4] = {};
  const short* qbase = Q + (size_t)(b * SS + s0 + wrow + fr) * HH + h * HDD + fk;
  #pragma unroll
  for (int k0 = 0; k0 < 64; k0 += 32) {
    short8_t af[4], wf[4];
    #pragma unroll
    for (int i = 0; i < 4; i++)
      af[i] = *(const short8_t*)(qbase + (size_t)(i * 16) * HH + k0);
    #pragma unroll
    for (int j = 0; j < 4; j++)
      wf[j] = *(const short8_t*)(sB + (j * 16 + fr) * 72 + fk + k0);
    #pragma unroll
    for (int i = 0; i < 4; i++) {
      #pragma unroll
      for (int j = 0; j < 4; j++) {
        acc[i][j] = __builtin_amdgcn_mfma_f32_16x16x32_bf16(af[i], wf[j], acc[i][j], 0, 0, 0);
      }
    }
  }

  const int cr = (lane >> 4) * 4, cc = lane & 15;
  short* cp = ctx + ((size_t)(b * SS + s0)) * HH + h * HDD;
  #pragma unroll
  for (int j = 0; j < 4; j++) {
    const int col = j * 16 + cc;
    #pragma unroll
    for (int i = 0; i < 4; i++) {
      #pragma unroll
      for (int r = 0; r < 4; r++) {
        const int row = wrow + i * 16 + cr + r;
        cp[(size_t)row * HH + col] = f2bf(acc[i][j][r] * sz[row]);
      }
    }
  }
}

// ---------------- LayerNorm(P + x) * gamma + beta ----------------
__global__ __launch_bounds__(256) void ln_kernel(
    const short* __restrict__ P, const float* __restrict__ x,
    const float* __restrict__ gamma, const float* __restrict__ beta,
    float* __restrict__ out)
{
  const int row = blockIdx.x;
  const int t = threadIdx.x;
  const short* pr = P + (size_t)row * HH;
  const float* xr = x + (size_t)row * HH;
  short4 p4 = ((const short4*)pr)[t];
  float4 x4 = ((const float4*)xr)[t];
  float h0 = bf2f(p4.x) + x4.x;
  float h1 = bf2f(p4.y) + x4.y;
  float h2 = bf2f(p4.z) + x4.z;
  float h3 = bf2f(p4.w) + x4.w;
  float s1 = h0 + h1 + h2 + h3;
  float s2 = h0*h0 + h1*h1 + h2*h2 + h3*h3;
  #pragma unroll
  for (int o = 32; o > 0; o >>= 1) {
    s1 += __shfl_xor(s1, o);
    s2 += __shfl_xor(s2, o);
  }
  __shared__ float red[8];
  const int wv = t >> 6, ln = t & 63;
  if (ln == 0) { red[wv] = s1; red[4 + wv] = s2; }
  __syncthreads();
  const float S1 = red[0] + red[1] + red[2] + red[3];
  const float S2 = red[4] + red[5] + red[6] + red[7];
  const float mu  = S1 * (1.f / HH);
  const float var = S2 * (1.f / HH) - mu * mu;
  const float inv = rsqrtf(var + 1e-12f);
  float4 g4 = ((const float4*)gamma)[t];
  float4 b4 = ((const float4*)beta)[t];
  float4 o4;
  o4.x = (h0 - mu) * inv * g4.x + b4.x;
  o4.y = (h1 - mu) * inv * g4.y + b4.y;
  o4.z = (h2 - mu) * inv * g4.z + b4.z;
  o4.w = (h3 - mu) * inv * g4.w + b4.w;
  ((float4*)(out + (size_t)row * HH))[t] = o4;
}

extern "C" void kernel_launch(void* const* d_in, const int* in_sizes, int n_in,
                              void* d_out, int out_size, void* d_ws, size_t ws_size,
                              hipStream_t stream)
{
  const float* x     = (const float*)d_in[0];
  // d_in[1] = attention_mask: unused (all zeros; reference ignores it)
  const float* Wq    = (const float*)d_in[2];
  const float* bq    = (const float*)d_in[3];
  const float* Wk    = (const float*)d_in[4];
  const float* bk    = (const float*)d_in[5];
  const float* Wv    = (const float*)d_in[6];
  const float* bv    = (const float*)d_in[7];
  const float* Wd    = (const float*)d_in[8];
  const float* bd    = (const float*)d_in[9];
  const float* gamma = (const float*)d_in[10];
  const float* beta  = (const float*)d_in[11];
  float* out = (float*)d_out;

  char* ws = (char*)d_ws;
  const size_t MB64 = 67108864;
  short* xb  = (short*)(ws + 0 * MB64);
  short* Qb  = (short*)(ws + 1 * MB64);
  short* Kb  = (short*)(ws + 2 * MB64);
  short* Vb  = (short*)(ws + 3 * MB64);
  short* Cb  = (short*)(ws + 4 * MB64);
  short* Wqb = (short*)(ws + 5 * MB64 + 0 * 2097152);
  short* Wkb = (short*)(ws + 5 * MB64 + 1 * 2097152);
  short* Wvb = (short*)(ws + 5 * MB64 + 2 * 2097152);
  short* Wdb = (short*)(ws + 5 * MB64 + 3 * 2097152);
  short* kvbf= (short*)(ws + 5 * MB64 + 4 * 2097152);
  float* ksb = (float*)(ws + 5 * MB64 + 5 * 2097152);
  // kv partials overlay Cb region (not live until ctx_mfma)
  float* kvpart = (float*)(ws + 4 * MB64);
  float* kspart = kvpart + (size_t)128 * KVSPLIT * 4096;
  short* Pb  = Qb;  // Q dead after ctx_mfma

  cvt_bf16<<<(MM * HH / 4) / 256, 256, 0, stream>>>(x,  xb,  MM * HH / 4);
  cvt_bf16<<<(HH * HH / 4) / 256, 256, 0, stream>>>(Wq, Wqb, HH * HH / 4);
  cvt_bf16<<<(HH * HH / 4) / 256, 256, 0, stream>>>(Wk, Wkb, HH * HH / 4);
  cvt_bf16<<<(HH * HH / 4) / 256, 256, 0, stream>>>(Wv, Wvb, HH * HH / 4);
  cvt_bf16<<<(HH * HH / 4) / 256, 256, 0, stream>>>(Wd, Wdb, HH * HH / 4);

  qkv_gemm<<<dim3(12, MM / BMt), 512, 0, stream>>>(xb, Wqb, Wkb, Wvb, bq, bk, bv, Qb, Kb, Vb);

  kv_part_kernel<<<dim3(NHH, BB, KVSPLIT), 256, 0, stream>>>(Kb, Vb, kvpart, kspart);
  kv_reduce_kernel<<<BB * NHH, 256, 0, stream>>>(kvpart, kspart, kvbf, ksb);
  ctx_mfma<<<dim3(SS / 256, NHH, BB), 256, 0, stream>>>(Qb, kvbf, ksb, Cb);

  dproj_gemm<<<dim3(HH / BNt, MM / BMt), 512, 0, stream>>>(Cb, Wdb, bd, Pb);
  ln_kernel<<<MM, 256, 0, stream>>>(Pb, x, gamma, beta, out);
}

// Round 6
// 708.969 us; speedup vs baseline: 1.3280x; 1.0024x over previous
//
#include <hip/hip_runtime.h>
#include <cstdint>
#include <cstddef>

#define BB 8
#define SS 4096
#define HH 1024
#define NHH 16
#define HDD 64
#define MM (BB*SS)   // 32768
#define KVSPLIT 16

#define BMt 256
#define BNt 256
#define BKt 64
#define NTt (HH/BKt)  // 16

typedef __attribute__((ext_vector_type(8))) short short8_t;
typedef __attribute__((ext_vector_type(4))) float f32x4;

__device__ __forceinline__ float bf2f(short u) {
  unsigned int x = ((unsigned int)(unsigned short)u) << 16;
  return __uint_as_float(x);
}
__device__ __forceinline__ short f2bf(float f) {
  unsigned int u = __float_as_uint(f);
  u += 0x7FFFu + ((u >> 16) & 1u);
  return (short)(u >> 16);
}

__device__ __forceinline__ void gload_lds16(const void* g, void* l) {
  __builtin_amdgcn_global_load_lds(
      (const __attribute__((address_space(1))) void*)g,
      (__attribute__((address_space(3))) void*)l, 16, 0, 0);
}

// ---------------- fp32 -> bf16 convert (vectorized) ----------------
__global__ void cvt_bf16(const float* __restrict__ in, short* __restrict__ out, int n4) {
  int i = blockIdx.x * blockDim.x + threadIdx.x;
  if (i >= n4) return;
  float4 v = ((const float4*)in)[i];
  short4 o;
  o.x = f2bf(v.x); o.y = f2bf(v.y); o.z = f2bf(v.z); o.w = f2bf(v.w);
  ((short4*)out)[i] = o;
}

// ---------------- 256x256 m201-template GEMM body: C = act(A @ W^T + bias) ----------------
// Faithful 8-phase/2-K-tile port (learn_hip m201, 62% MfmaUtil on this chip):
// per phase {4-8 ds_reads (own operands) -> stage 1-2 half-tiles -> barrier ->
// lgkmcnt(0)+sched_barrier -> setprio(1) -> 16 MFMA -> setprio(0) -> barrier}.
// ONE counted vmcnt(6) per K-tile at end-p3 (3 half-tiles stay in flight).
// Stage rota (tile t): p0: A(t+1)h1 | p2: A(t+2)h0+B(t+2)h0 | p3: B(t+2)h1.
// Ledger: end-p3(t) has 14 outstanding; vmcnt(6) drains exactly tile t+1's four
// halves. Prologue: tile0 (8) + tile1 h0-trio (6) -> vmcnt(6). Tail: vmcnt(0) at
// kt=NTt-2. All stages barrier-separated from last reads of overwritten regions.
// (slot ^ row&7) LDS swizzle, inverse-swizzled global source (conflicts = 0).
__device__ __forceinline__ void gemm256_body(
    const short* __restrict__ A, const short* __restrict__ W,
    const float* __restrict__ bias, short* __restrict__ C,
    int m0, int n0, bool act)
{
  __shared__ __align__(16) char smem[131072];  // [A: 2x32KB][B: 2x32KB]

  const int tid  = threadIdx.x;
  const int lane = tid & 63;
  const int wm2  = (tid >> 6) >> 2;   // 0..1 row-quarter within active half
  const int wn   = (tid >> 6) & 3;    // 0..3 64-col group
  const int fr   = lane & 15;
  const int fg   = lane >> 4;         // 0..3

  // staging: unit = 64 rows x 64 shorts (8KB); thread -> (row=tid>>3, slot=tid&7)
  const int urow  = tid >> 3;
  const int uslot = tid & 7;
  const short* Asrc = A + (size_t)(m0 + urow) * HH + ((uslot ^ (urow & 7)) << 3);
  const short* Bsrc = W + (size_t)(n0 + urow) * HH + ((uslot ^ (urow & 7)) << 3);
  char* Adst = smem + tid * 16;            // linear LDS dest
  char* Bdst = smem + 65536 + tid * 16;

#define STG_AH(b, kt, h) do { \
    gload_lds16(Asrc + (size_t)((h)*2+0) * 64 * HH + (kt) * 64, Adst + (b) * 32768 + ((h)*2+0) * 8192); \
    gload_lds16(Asrc + (size_t)((h)*2+1) * 64 * HH + (kt) * 64, Adst + (b) * 32768 + ((h)*2+1) * 8192); \
  } while (0)
#define STG_BH(b, kt, h) do { \
    gload_lds16(Bsrc + (size_t)((h)*2+0) * 64 * HH + (kt) * 64, Bdst + (b) * 32768 + ((h)*2+0) * 8192); \
    gload_lds16(Bsrc + (size_t)((h)*2+1) * 64 * HH + (kt) * 64, Bdst + (b) * 32768 + ((h)*2+1) * 8192); \
  } while (0)

  // ds_read bases: LDS byte = buf*32768 + half*16384 + (row&127)*128 + (slot^(row&7))*16
  const char* pA = smem + fr * 128;
  const char* pB = smem + 65536 + (wn * 64 + fr) * 128;
  const int sw0 = ((fg)     ^ (fr & 7)) << 4;   // k-slice 0 slots 0..3
  const int sw1 = ((4 + fg) ^ (fr & 7)) << 4;   // k-slice 1 slots 4..7
  const int rowA = wm2 * 8192;                  // wave's 64-row quarter within half

#define DSR_A(RA, OFS, SW) do { \
    _Pragma("unroll") \
    for (int i_ = 0; i_ < 4; i_++) (RA)[i_] = *(const short8_t*)(pA + (OFS) + i_ * 2048 + (SW)); \
  } while (0)
#define DSR_B(RB, OFS, SW) do { \
    _Pragma("unroll") \
    for (int j_ = 0; j_ < 4; j_++) (RB)[j_] = *(const short8_t*)(pB + (OFS) + j_ * 2048 + (SW)); \
  } while (0)
#define MFMA16(OFS, RA, RB) do { \
    _Pragma("unroll") \
    for (int i_ = 0; i_ < 4; i_++) { \
      _Pragma("unroll") \
      for (int j_ = 0; j_ < 4; j_++) \
        acc[(OFS) + i_][j_] = __builtin_amdgcn_mfma_f32_16x16x32_bf16((RA)[i_], (RB)[j_], acc[(OFS) + i_][j_], 0, 0, 0); \
    } \
  } while (0)
#define LGKM0() asm volatile("s_waitcnt lgkmcnt(0)" ::: "memory")
#define VMC6()  asm volatile("s_waitcnt vmcnt(6)" ::: "memory")
#define VMC0()  asm volatile("s_waitcnt vmcnt(0)" ::: "memory")
#define SBAR()  __builtin_amdgcn_s_barrier()
#define SCHED() __builtin_amdgcn_sched_barrier(0)
#define PRIO1() __builtin_amdgcn_s_setprio(1)
#define PRIO0() __builtin_amdgcn_s_setprio(0)

  f32x4 acc[8][4] = {};
  short8_t af[4], bf0[4], bf1[4];

  // ---- prologue: tile0 full (8 loads) then tile1 h0-trio (6 loads); vmcnt(6) ----
  STG_AH(0, 0, 0); STG_BH(0, 0, 0); STG_BH(0, 0, 1); STG_AH(0, 0, 1);
  SCHED();  // pin group boundary so vmcnt(6) drains exactly tile0's 8
  STG_AH(1, 1, 0); STG_BH(1, 1, 0); STG_BH(1, 1, 1);
  VMC6();
  SBAR(); SCHED();

  #pragma unroll 2
  for (int kt = 0; kt < NTt - 2; ++kt) {
    const int ao = (kt & 1) * 32768;
    // ---- p0: h0 ks0 (+ stage A(t+1)h1) ----
    DSR_B(bf0, ao, sw0);
    DSR_A(af, ao + rowA, sw0);
    STG_AH((kt & 1) ^ 1, kt + 1, 1);
    SCHED(); SBAR();
    LGKM0(); SCHED();
    PRIO1(); MFMA16(0, af, bf0); PRIO0();
    SBAR(); SCHED();
    // ---- p1: h0 ks1 ----
    DSR_B(bf1, ao, sw1);
    DSR_A(af, ao + rowA, sw1);
    SCHED(); SBAR();
    LGKM0(); SCHED();
    PRIO1(); MFMA16(0, af, bf1); PRIO0();
    SBAR(); SCHED();
    // ---- p2: h1 ks0 (+ stage A(t+2)h0, B(t+2)h0; regions last read at p1) ----
    DSR_A(af, ao + 16384 + rowA, sw0);
    STG_AH(kt & 1, kt + 2, 0); STG_BH(kt & 1, kt + 2, 0);
    SCHED(); SBAR();
    LGKM0(); SCHED();
    PRIO1(); MFMA16(4, af, bf0); PRIO0();
    SBAR(); SCHED();
    // ---- p3: h1 ks1 (+ stage B(t+2)h1); single counted gate per K-tile ----
    DSR_A(af, ao + 16384 + rowA, sw1);
    STG_BH(kt & 1, kt + 2, 1);
    SCHED(); SBAR();
    LGKM0(); SCHED();
    PRIO1(); MFMA16(4, af, bf1); PRIO0();
    VMC6();   // drains tile t+1's four halves; leaves tile t+2's three in flight
    SBAR(); SCHED();
  }

  // ---- peeled kt = NTt-2: stage only A(NTt-1)h1 at p0; gate vmcnt(0) ----
  {
    const int ao = ((NTt - 2) & 1) * 32768;
    DSR_B(bf0, ao, sw0);
    DSR_A(af, ao + rowA, sw0);
    STG_AH(((NTt - 2) & 1) ^ 1, NTt - 1, 1);
    SCHED(); SBAR();
    LGKM0(); SCHED();
    PRIO1(); MFMA16(0, af, bf0); PRIO0();
    SBAR(); SCHED();
    DSR_B(bf1, ao, sw1);
    DSR_A(af, ao + rowA, sw1);
    SCHED(); SBAR();
    LGKM0(); SCHED();
    PRIO1(); MFMA16(0, af, bf1); PRIO0();
    SBAR(); SCHED();
    DSR_A(af, ao + 16384 + rowA, sw0);
    SCHED(); SBAR();
    LGKM0(); SCHED();
    PRIO1(); MFMA16(4, af, bf0); PRIO0();
    SBAR(); SCHED();
    DSR_A(af, ao + 16384 + rowA, sw1);
    SCHED(); SBAR();
    LGKM0(); SCHED();
    PRIO1(); MFMA16(4, af, bf1); PRIO0();
    VMC0();
    SBAR(); SCHED();
  }
  // ---- peeled kt = NTt-1: no stages, no gate ----
  {
    const int ao = ((NTt - 1) & 1) * 32768;
    DSR_B(bf0, ao, sw0);
    DSR_A(af, ao + rowA, sw0);
    SCHED(); SBAR();
    LGKM0(); SCHED();
    PRIO1(); MFMA16(0, af, bf0); PRIO0();
    SBAR(); SCHED();
    DSR_B(bf1, ao, sw1);
    DSR_A(af, ao + rowA, sw1);
    SCHED(); SBAR();
    LGKM0(); SCHED();
    PRIO1(); MFMA16(0, af, bf1); PRIO0();
    SBAR(); SCHED();
    DSR_A(af, ao + 16384 + rowA, sw0);
    SCHED(); SBAR();
    LGKM0(); SCHED();
    PRIO1(); MFMA16(4, af, bf0); PRIO0();
    SBAR(); SCHED();
    DSR_A(af, ao + 16384 + rowA, sw1);
    SCHED(); SBAR();
    LGKM0(); SCHED();
    PRIO1(); MFMA16(4, af, bf1); PRIO0();
    SBAR(); SCHED();
  }
#undef STG_AH
#undef STG_BH

  // ---- epilogue: bias+act, two-pass LDS transpose (stride 264), short8 stores ----
  short* sC = (short*)smem;   // 128 x 264 x 2B = 67584 B
  float bvj[4];
  #pragma unroll
  for (int j = 0; j < 4; j++) bvj[j] = bias[n0 + wn * 64 + j * 16 + fr];

  #pragma unroll
  for (int h = 0; h < 2; ++h) {
    #pragma unroll
    for (int i = 0; i < 4; i++) {
      #pragma unroll
      for (int j = 0; j < 4; j++) {
        const int col = wn * 64 + j * 16 + fr;
        #pragma unroll
        for (int r = 0; r < 4; r++) {
          float v = acc[h * 4 + i][j][r] + bvj[j];
          if (act) v = (v > 0.f) ? (v + 1.f) : __expf(v);
          sC[(wm2 * 64 + i * 16 + fg * 4 + r) * 264 + col] = f2bf(v);
        }
      }
    }
    __syncthreads();
    const int crow = tid >> 5;          // 0..15
    const int cch  = (tid & 31) * 8;    // short offset, 32 x 16B = 512B row
    #pragma unroll
    for (int p = 0; p < 8; p++) {
      const int row = p * 16 + crow;
      *(short8_t*)(C + (size_t)(m0 + h * 128 + row) * HH + n0 + cch) =
          *(const short8_t*)(sC + row * 264 + cch);
    }
    __syncthreads();
  }
#undef DSR_A
#undef DSR_B
#undef MFMA16
#undef LGKM0
#undef VMC6
#undef VMC0
#undef SBAR
#undef SCHED
#undef PRIO1
#undef PRIO0
}

// fused QKV: blockIdx.x = which*4 + ncol; consecutive x-blocks share the A tile (L2 reuse)
__global__ __launch_bounds__(512, 2) void qkv_gemm(
    const short* __restrict__ xb,
    const short* __restrict__ Wqb, const short* __restrict__ Wkb, const short* __restrict__ Wvb,
    const float* __restrict__ bq, const float* __restrict__ bk, const float* __restrict__ bv,
    short* __restrict__ Qo, short* __restrict__ Ko, short* __restrict__ Vo)
{
  const int which = blockIdx.x >> 2;
  const int n0 = (blockIdx.x & 3) * BNt;
  const int m0 = blockIdx.y * BMt;
  const short* W  = (which == 0) ? Wqb : (which == 1) ? Wkb : Wvb;
  const float* bs = (which == 0) ? bq  : (which == 1) ? bk  : bv;
  short* C        = (which == 0) ? Qo  : (which == 1) ? Ko  : Vo;
  gemm256_body(xb, W, bs, C, m0, n0, which < 2);
}

__global__ __launch_bounds__(512, 2) void dproj_gemm(
    const short* __restrict__ A, const short* __restrict__ W,
    const float* __restrict__ bias, short* __restrict__ C)
{
  gemm256_body(A, W, bias, C, blockIdx.y * BMt, blockIdx.x * BNt, false);
}

// ---------------- kv partials over S-splits ----------------
__global__ __launch_bounds__(256) void kv_part_kernel(
    const short* __restrict__ K_, const short* __restrict__ V_,
    float* __restrict__ kvpart, float* __restrict__ kspart)
{
  __shared__ __align__(16) float sK[32 * 64];
  __shared__ __align__(16) float sV[32 * 64];
  const int h = blockIdx.x, b = blockIdx.y, sp = blockIdx.z;
  const int t = threadIdx.x;
  const int m = t & 63;
  const int dg = (t >> 6) * 16;
  const int lrow = t >> 3;
  const int lcol = (t & 7) * 8;
  const int SC = SS / KVSPLIT;
  float acc[16] = {};
  float ks = 0.f;
  const size_t base = ((size_t)b * SS + (size_t)sp * SC) * HH + (size_t)h * HDD;
  const short* Kp = K_ + base + (size_t)lrow * HH + lcol;
  const short* Vp = V_ + base + (size_t)lrow * HH + lcol;

  for (int sc = 0; sc < SC; sc += 32) {
    short8_t k8 = *(const short8_t*)(Kp + (size_t)sc * HH);
    short8_t v8 = *(const short8_t*)(Vp + (size_t)sc * HH);
    __syncthreads();
    #pragma unroll
    for (int j = 0; j < 8; j++) {
      sK[lrow * 64 + lcol + j] = bf2f(k8[j]);
      sV[lrow * 64 + lcol + j] = bf2f(v8[j]);
    }
    __syncthreads();
    if (t < 64) {
      #pragma unroll
      for (int ss = 0; ss < 32; ss++) ks += sK[ss * 64 + t];
    }
    #pragma unroll 4
    for (int ss = 0; ss < 32; ss++) {
      const float vm = sV[ss * 64 + m];
      const float* kr = sK + ss * 64 + dg;
      #pragma unroll
      for (int j = 0; j < 16; j++) acc[j] += kr[j] * vm;
    }
  }

  const int bh = b * NHH + h;
  float* kvp = kvpart + (size_t)(bh * KVSPLIT + sp) * 4096 + m * 64 + dg;
  #pragma unroll
  for (int j = 0; j < 16; j += 4) {
    f32x4 o;
    o[0] = acc[j]; o[1] = acc[j+1]; o[2] = acc[j+2]; o[3] = acc[j+3];
    *(f32x4*)(kvp + j) = o;
  }
  if (t < 64) kspart[(bh * KVSPLIT + sp) * 64 + t] = ks;
}

// ---------------- reduce partials -> kv bf16 [bh][m][d], ksum fp32 ----------------
__global__ __launch_bounds__(256) void kv_reduce_kernel(
    const float* __restrict__ kvpart, const float* __restrict__ kspart,
    short* __restrict__ kvbf, float* __restrict__ ksum)
{
  const int bh = blockIdx.x;
  const int t = threadIdx.x;
  const float* src = kvpart + (size_t)bh * KVSPLIT * 4096;
  #pragma unroll
  for (int i = 0; i < 4; i++) {
    const int idx = t + i * 256;  // f32x4 index within 4096
    f32x4 s = {};
    #pragma unroll 4
    for (int p = 0; p < KVSPLIT; p++)
      s += ((const f32x4*)(src + (size_t)p * 4096))[idx];
    short4 o;
    o.x = f2bf(s[0]); o.y = f2bf(s[1]); o.z = f2bf(s[2]); o.w = f2bf(s[3]);
    ((short4*)(kvbf + (size_t)bh * 4096))[idx] = o;
  }
  if (t < 64) {
    float s = 0.f;
    #pragma unroll
    for (int p = 0; p < KVSPLIT; p++) s += kspart[(bh * KVSPLIT + p) * 64 + t];
    ksum[bh * 64 + t] = s + 1e-6f;
  }
}

// ---------------- ctx via MFMA: per (b,h), ctx = diag(z) . Q[4096x64] @ kv[64x64]^T ----------------
__global__ __launch_bounds__(256) void ctx_mfma(
    const short* __restrict__ Q, const short* __restrict__ kvbf,
    const float* __restrict__ ksum, short* __restrict__ ctx)
{
  __shared__ __align__(16) short sB[64 * 72];
  __shared__ float sks[64];
  __shared__ float sz[256];
  const int b = blockIdx.z, h = blockIdx.y;
  const int t = threadIdx.x;
  const int lane = t & 63, wave = t >> 6;
  const int s0 = blockIdx.x * 256;
  const int bh = b * NHH + h;

  { // stage kv -> LDS (padded)
    const short8_t* src = (const short8_t*)(kvbf + (size_t)bh * 4096);
    const int m = t >> 2, c = (t & 3) * 16;
    short8_t v0 = src[t * 2], v1 = src[t * 2 + 1];
    *(short8_t*)(sB + m * 72 + c)     = v0;
    *(short8_t*)(sB + m * 72 + c + 8) = v1;
  }
  if (t < 64) sks[t] = ksum[bh * 64 + t];
  __syncthreads();

  { // per-token normalizer z = 1/(q . ksum)
    const short* qp = Q + (size_t)(b * SS + s0 + t) * HH + h * HDD;
    float zden = 0.f;
    #pragma unroll
    for (int i = 0; i < 8; i++) {
      short8_t q8 = *(const short8_t*)(qp + i * 8);
      #pragma unroll
      for (int j = 0; j < 8; j++) zden += bf2f(q8[j]) * sks[i * 8 + j];
    }
    sz[t] = 1.f / zden;
  }
  __syncthreads();

  const int fr = lane & 15, fk = (lane >> 4) * 8;
  const int wrow = wave * 64;
  f32x4 acc[4][4] = {};
  const short* qbase = Q + (size_t)(b * SS + s0 + wrow + fr) * HH + h * HDD + fk;
  #pragma unroll
  for (int k0 = 0; k0 < 64; k0 += 32) {
    short8_t af[4], wf[4];
    #pragma unroll
    for (int i = 0; i < 4; i++)
      af[i] = *(const short8_t*)(qbase + (size_t)(i * 16) * HH + k0);
    #pragma unroll
    for (int j = 0; j < 4; j++)
      wf[j] = *(const short8_t*)(sB + (j * 16 + fr) * 72 + fk + k0);
    #pragma unroll
    for (int i = 0; i < 4; i++) {
      #pragma unroll
      for (int j = 0; j < 4; j++) {
        acc[i][j] = __builtin_amdgcn_mfma_f32_16x16x32_bf16(af[i], wf[j], acc[i][j], 0, 0, 0);
      }
    }
  }

  const int cr = (lane >> 4) * 4, cc = lane & 15;
  short* cp = ctx + ((size_t)(b * SS + s0)) * HH + h * HDD;
  #pragma unroll
  for (int j = 0; j < 4; j++) {
    const int col = j * 16 + cc;
    #pragma unroll
    for (int i = 0; i < 4; i++) {
      #pragma unroll
      for (int r = 0; r < 4; r++) {
        const int row = wrow + i * 16 + cr + r;
        cp[(size_t)row * HH + col] = f2bf(acc[i][j][r] * sz[row]);
      }
    }
  }
}

// ---------------- LayerNorm(P + x) * gamma + beta ----------------
__global__ __launch_bounds__(256) void ln_kernel(
    const short* __restrict__ P, const float* __restrict__ x,
    const float* __restrict__ gamma, const float* __restrict__ beta,
    float* __restrict__ out)
{
  const int row = blockIdx.x;
  const int t = threadIdx.x;
  const short* pr = P + (size_t)row * HH;
  const float* xr = x + (size_t)row * HH;
  short4 p4 = ((const short4*)pr)[t];
  float4 x4 = ((const float4*)xr)[t];
  float h0 = bf2f(p4.x) + x4.x;
  float h1 = bf2f(p4.y) + x4.y;
  float h2 = bf2f(p4.z) + x4.z;
  float h3 = bf2f(p4.w) + x4.w;
  float s1 = h0 + h1 + h2 + h3;
  float s2 = h0*h0 + h1*h1 + h2*h2 + h3*h3;
  #pragma unroll
  for (int o = 32; o > 0; o >>= 1) {
    s1 += __shfl_xor(s1, o);
    s2 += __shfl_xor(s2, o);
  }
  __shared__ float red[8];
  const int wv = t >> 6, ln = t & 63;
  if (ln == 0) { red[wv] = s1; red[4 + wv] = s2; }
  __syncthreads();
  const float S1 = red[0] + red[1] + red[2] + red[3];
  const float S2 = red[4] + red[5] + red[6] + red[7];
  const float mu  = S1 * (1.f / HH);
  const float var = S2 * (1.f / HH) - mu * mu;
  const float inv = rsqrtf(var + 1e-12f);
  float4 g4 = ((const float4*)gamma)[t];
  float4 b4 = ((const float4*)beta)[t];
  float4 o4;
  o4.x = (h0 - mu) * inv * g4.x + b4.x;
  o4.y = (h1 - mu) * inv * g4.y + b4.y;
  o4.z = (h2 - mu) * inv * g4.z + b4.z;
  o4.w = (h3 - mu) * inv * g4.w + b4.w;
  ((float4*)(out + (size_t)row * HH))[t] = o4;
}

extern "C" void kernel_launch(void* const* d_in, const int* in_sizes, int n_in,
                              void* d_out, int out_size, void* d_ws, size_t ws_size,
                              hipStream_t stream)
{
  const float* x     = (const float*)d_in[0];
  // d_in[1] = attention_mask: unused (all zeros; reference ignores it)
  const float* Wq    = (const float*)d_in[2];
  const float* bq    = (const float*)d_in[3];
  const float* Wk    = (const float*)d_in[4];
  const float* bk    = (const float*)d_in[5];
  const float* Wv    = (const float*)d_in[6];
  const float* bv    = (const float*)d_in[7];
  const float* Wd    = (const float*)d_in[8];
  const float* bd    = (const float*)d_in[9];
  const float* gamma = (const float*)d_in[10];
  const float* beta  = (const float*)d_in[11];
  float* out = (float*)d_out;

  char* ws = (char*)d_ws;
  const size_t MB64 = 67108864;
  short* xb  = (short*)(ws + 0 * MB64);
  short* Qb  = (short*)(ws + 1 * MB64);
  short* Kb  = (short*)(ws + 2 * MB64);
  short* Vb  = (short*)(ws + 3 * MB64);
  short* Cb  = (short*)(ws + 4 * MB64);
  short* Wqb = (short*)(ws + 5 * MB64 + 0 * 2097152);
  short* Wkb = (short*)(ws + 5 * MB64 + 1 * 2097152);
  short* Wvb = (short*)(ws + 5 * MB64 + 2 * 2097152);
  short* Wdb = (short*)(ws + 5 * MB64 + 3 * 2097152);
  short* kvbf= (short*)(ws + 5 * MB64 + 4 * 2097152);
  float* ksb = (float*)(ws + 5 * MB64 + 5 * 2097152);
  // kv partials overlay Cb region (not live until ctx_mfma)
  float* kvpart = (float*)(ws + 4 * MB64);
  float* kspart = kvpart + (size_t)128 * KVSPLIT * 4096;
  short* Pb  = Qb;  // Q dead after ctx_mfma

  cvt_bf16<<<(MM * HH / 4) / 256, 256, 0, stream>>>(x,  xb,  MM * HH / 4);
  cvt_bf16<<<(HH * HH / 4) / 256, 256, 0, stream>>>(Wq, Wqb, HH * HH / 4);
  cvt_bf16<<<(HH * HH / 4) / 256, 256, 0, stream>>>(Wk, Wkb, HH * HH / 4);
  cvt_bf16<<<(HH * HH / 4) / 256, 256, 0, stream>>>(Wv, Wvb, HH * HH / 4);
  cvt_bf16<<<(HH * HH / 4) / 256, 256, 0, stream>>>(Wd, Wdb, HH * HH / 4);

  qkv_gemm<<<dim3(12, MM / BMt), 512, 0, stream>>>(xb, Wqb, Wkb, Wvb, bq, bk, bv, Qb, Kb, Vb);

  kv_part_kernel<<<dim3(NHH, BB, KVSPLIT), 256, 0, stream>>>(Kb, Vb, kvpart, kspart);
  kv_reduce_kernel<<<BB * NHH, 256, 0, stream>>>(kvpart, kspart, kvbf, ksb);
  ctx_mfma<<<dim3(SS / 256, NHH, BB), 256, 0, stream>>>(Qb, kvbf, ksb, Cb);

  dproj_gemm<<<dim3(HH / BNt, MM / BMt), 512, 0, stream>>>(Cb, Wdb, bd, Pb);
  ln_kernel<<<MM, 256, 0, stream>>>(Pb, x, gamma, beta, out);
}